// Round 11
// baseline (218.645 us; speedup 1.0000x reference)
//
#include <hip/hip_runtime.h>
#include <math.h>

// ---------------------------------------------------------------------------
// DGCNN-style network, B=8, N=2048, K=20, eval-mode BN.
// Round 22: knn revert+improve. r20/21 VGPR diet REGRESSED (43->52us,
// total 215): occupancy 26->65% but recompute doubled VALU work -> kernel
// became VALU-throughput-bound. Lesson: cut VALU work, don't buy occupancy
// with it. This round: restore r18 keys[32] single-pass cache AND store
// points as float4(x,y,z,|p|^2) in LDS (pw precomputed once per point:
// ~13->8 VALU ops/key, ds_read_b128 vs b64+b32). LDS 29->37KB is free now
// (VGPR-limited to 2 blocks/CU); old r10 float4 regression was the 256-thr
// config's occupancy cliff, not the layout.
// r19: BM=64 fused gather-GEMMs. r18: knn 512-thr 1-q/wave (-8us).
// r17: batch-aligned XCD swizzle (-8us). r16: single-gather + l1 reuse
// (-5.6us). r13: gemm5 8-phase 256x256 m201 schedule (-10us).
// Trick (verified r1-r10): max_k lrelu(bn(h)) == lrelu(bn(max_k h)) for bn
// scale>=0, min_k when scale<0 -> gather reduces max AND min of pre-BN y.
// ---------------------------------------------------------------------------

#define WS_IDX      0            // int[16384*20]            1,310,720 B
#define WS_Y16      1310720     // half[16384*256]          8,388,608 B  (y16a)
#define WS_XCAT16   9699328     // half[16384*512]          16,777,216 B
#define WS_W16      26476544    // half[569344]             1,138,688 B
#define WS_FMAX     27615232    // uint[8*1024]             32,768 B
#define WS_FSUM     27648000    // float[8*1024]            32,768 B
#define WS_A1       27680768    // float[8*512]             16,384 B
#define WS_A2       27697152    // float[8*256]             8,192 B
#define WS_Y16B     27705344    // half[16384*128]          4,194,304 B  (y16b)
// total ~31.9 MB

typedef _Float16 f16x8 __attribute__((ext_vector_type(8)));
typedef float f32x4 __attribute__((ext_vector_type(4)));

struct F3 { float x, y, z; };

__device__ __forceinline__ float lrelu(float v) { return (v >= 0.f) ? v : 0.2f * v; }
__device__ __forceinline__ unsigned sortable_f32(float f) {
  unsigned b = __float_as_uint(f);
  return b ^ (((unsigned)((int)b >> 31)) | 0x80000000u);
}
__device__ __forceinline__ float desort_f32(unsigned u) {
  unsigned b = (u & 0x80000000u) ? (u ^ 0x80000000u) : ~u;
  return __uint_as_float(b);
}
// batch-aligned XCD swizzle: i%8 -> XCD under round-robin dispatch; with
// per-batch chunk = nwg/8, batch(bid) = i%8. Bijective for nwg%8==0.
__device__ __forceinline__ int xcd_swz(int i, int nwg) {
  return (i & 7) * (nwg >> 3) + (i >> 3);
}

// --------------------- KNN + edge1 + prep (one dispatch) --------------------
// Blocks [0,2048): 512 thr, 8 waves, 1 query/wave. pts as float4(x,y,z,|p|2)
// in LDS; single distance pass caches 32 sortable keys/lane in regs +
// lane-max -> 16-iter ballot bisection -> T; ballot-prefix compaction;
// 64-lane bitonic sort == exact jax.lax.top_k tie-break; C>60 exact path
// from cached keys. Then edge1 (lane=channel) -> xcat[:,0:64].
// Blocks [2048,2191): W2..W5 -> fp16 w16; zero fmax/fsum.
__global__ __launch_bounds__(512) void knn_prep_kernel(
    const float* __restrict__ x, const float* __restrict__ W1,
    const float* __restrict__ g1, const float* __restrict__ b1,
    const float* __restrict__ W2, const float* __restrict__ W3,
    const float* __restrict__ W4, const float* __restrict__ W5,
    _Float16* __restrict__ w16, unsigned* __restrict__ fzero,
    int* __restrict__ idxo, _Float16* __restrict__ xcat) {
  __shared__ float4 pts_s[2048];                // 32768 B
  __shared__ unsigned long long cand_s[8][60];  // 3840 B
  __shared__ int sel_s[8][20];                  // 640 B
  int tid = threadIdx.x;

  if (blockIdx.x >= 2048) {  // ---- prep branch: 143 blocks x 4096 items ----
    int bid = blockIdx.x - 2048;
#pragma unroll
    for (int t = 0; t < 8; ++t) {
      int i = bid * 4096 + t * 512 + tid;
      if (i < 4096) w16[i] = (_Float16)W2[i];
      else if (i < 12288) w16[i] = (_Float16)W3[i - 4096];
      else if (i < 45056) w16[i] = (_Float16)W4[i - 12288];
      else if (i < 569344) w16[i] = (_Float16)W5[i - 45056];
      else fzero[i - 569344] = 0u;  // fmax (sortable 0 < any finite) + fsum
    }
    return;
  }

  int wv = tid >> 6, lane = tid & 63;  // wv 0..7, one query per wave
  int qbase = blockIdx.x * 8;
  int b = qbase >> 11;
  int nbase = qbase & 2047;
  const float* xb = x + b * 6144;
#pragma unroll
  for (int i = 0; i < 4; ++i) {
    int m = tid + i * 512;
    float px = xb[m], py = xb[2048 + m], pz = xb[4096 + m];
    pts_s[m] = make_float4(px, py, pz, px * px + py * py + pz * pz);
  }
  __syncthreads();

  float4 q = pts_s[nbase + wv];
  unsigned keys[32];
  unsigned lmax = 0u;
#pragma unroll
  for (int j = 0; j < 32; ++j) {
    float4 p = pts_s[j * 64 + lane];
    float nd = 2.0f * (q.x * p.x + q.y * p.y + q.z * p.z) - q.w - p.w;
    unsigned key = sortable_f32(nd);
    keys[j] = key;
    lmax = (key > lmax) ? key : lmax;
  }
  unsigned lo = 0u, hi = 0x8001u;
  for (int it = 0; it < 16; ++it) {
    unsigned mid = (lo + hi + 1) >> 1;
    int cnt = __popcll(__ballot(lmax >= (mid << 16)));
    if (cnt >= 20) lo = mid; else hi = mid;
  }
  unsigned T = lo << 16;
  // ballot-prefix compaction (no atomics); cnt is wave-uniform
  unsigned cnt = 0u;
  unsigned long long below = (1ull << lane) - 1ull;
#pragma unroll
  for (int j = 0; j < 32; ++j) {
    int m = j * 64 + lane;
    bool pass = keys[j] >= T;
    unsigned long long mask = __ballot(pass);
    if (pass) {
      unsigned pos = cnt + (unsigned)__popcll(mask & below);
      if (pos < 60)
        cand_s[wv][pos] =
            (((unsigned long long)keys[j]) << 32) | (unsigned)(2047 - m);
    }
    cnt += (unsigned)__popcll(mask);
  }

  int row = qbase + wv;
  int outb = row * 20;
  unsigned C = cnt;  // wave-uniform
  if (C <= 60) {
    unsigned long long v = (lane < (int)C) ? ~cand_s[wv][lane] : ~0ull;
#pragma unroll
    for (int k = 2; k <= 64; k <<= 1) {
#pragma unroll
      for (int jj = k >> 1; jj > 0; jj >>= 1) {
        unsigned long long o = __shfl_xor(v, jj, 64);
        bool lower = (lane & jj) == 0;
        bool up = (lane & k) == 0;
        bool takeMin = (lower == up);
        bool sw = takeMin ? (o < v) : (o > v);
        v = sw ? o : v;
      }
    }
    if (lane < 20) {
      unsigned long long pack = ~v;
      int m = 2047 - (int)(pack & 0xFFFFFFFFu);
      idxo[outb + lane] = m;
      sel_s[wv][lane] = m;
    }
  } else {
    unsigned long long prev = ~0ull;
    for (int r = 0; r < 20; ++r) {
      unsigned long long best = 0ull;
#pragma unroll
      for (int j = 0; j < 32; ++j) {
        int m = j * 64 + lane;
        unsigned long long pk =
            (((unsigned long long)keys[j]) << 32) | (unsigned)(2047 - m);
        bool ok = (pk < prev) & (pk > best);
        best = ok ? pk : best;
      }
#pragma unroll
      for (int off = 1; off < 64; off <<= 1) {
        unsigned long long o = __shfl_xor(best, off, 64);
        best = (o > best) ? o : best;
      }
      int m = 2047 - (int)(best & 0xFFFFFFFFu);
      if (lane == 0) { idxo[outb + r] = m; sel_s[wv][r] = m; }
      prev = best;
    }
  }

  float w0 = W1[lane * 3 + 0], w1 = W1[lane * 3 + 1], w2 = W1[lane * 3 + 2];
  float inv = 1.0f / sqrtf(1.0f + 1e-5f);
  float sc = g1[lane] * inv, bi = b1[lane];
  {
    float mx = -3.4e38f, mn = 3.4e38f;
#pragma unroll
    for (int k = 0; k < 20; ++k) {
      float4 p = pts_s[sel_s[wv][k]];
      float v = w0 * p.x + w1 * p.y + w2 * p.z;
      mx = fmaxf(mx, v);
      mn = fminf(mn, v);
    }
    float v = (sc >= 0.0f) ? mx : mn;
    xcat[row * 512 + lane] = (_Float16)lrelu(sc * v + bi);
  }
}

// --------------- gather max/min + BN + lrelu -> fp16 (f16x8) ----------------
template <int C, int COFF>
__global__ __launch_bounds__(256) void gmax_kernel(const _Float16* __restrict__ y,
                                                   const int* __restrict__ idx,
                                                   const float* __restrict__ g,
                                                   const float* __restrict__ bb,
                                                   _Float16* __restrict__ xcat) {
  constexpr int TP = C / 8;
  int bxs = xcd_swz(blockIdx.x, gridDim.x);
  int e = bxs * 256 + threadIdx.x;
  int c8 = e & (TP - 1);
  int pg = e / TP;
  int b = pg >> 11;
  const int* ix = idx + pg * 20;
  int mm[20];
#pragma unroll
  for (int k = 0; k < 20; ++k) mm[k] = ix[k];
  int base = b * 2048 * C + c8 * 8;
  float mx[8], mn[8];
#pragma unroll
  for (int i = 0; i < 8; ++i) { mx[i] = -3.4e38f; mn[i] = 3.4e38f; }
#pragma unroll
  for (int k = 0; k < 20; ++k) {
    f16x8 v = *(const f16x8*)&y[base + mm[k] * C];
#pragma unroll
    for (int i = 0; i < 8; ++i) {
      float f = (float)v[i];
      mx[i] = fmaxf(mx[i], f);
      mn[i] = fminf(mn[i], f);
    }
  }
  float inv = 1.0f / sqrtf(1.0f + 1e-5f);
  f16x8 outv;
#pragma unroll
  for (int i = 0; i < 8; ++i) {
    float s = g[c8 * 8 + i] * inv;
    float v = (s >= 0.0f) ? mx[i] : mn[i];
    outv[i] = (_Float16)lrelu(s * v + bb[c8 * 8 + i]);
  }
  *(f16x8*)&xcat[pg * 512 + COFF + c8 * 8] = outv;
}

// ------------- fp16 MFMA GEMM (r7 exact): Y16 = Wh @ xcat-slice -------------
template <int CIN, int COUT, int XOFF>
__global__ __launch_bounds__(256) void gemm_mfma(const _Float16* __restrict__ Wh,
                                                 const _Float16* __restrict__ Xc,
                                                 _Float16* __restrict__ Y) {
  constexpr int BN = (COUT < 128) ? COUT : 128;
  constexpr int MT = (BN == 128) ? 4 : 2;
  __shared__ _Float16 Xs[128 * 40];
  __shared__ _Float16 Ws[BN * 40];
  int tid = threadIdx.x;
  int lane = tid & 63, w = tid >> 6;
  int wm = (BN == 128) ? (w & 1) : w;
  int wn = (BN == 128) ? (w >> 1) : 0;
  int col = lane & 15, quad = lane >> 4;
  int pg0 = xcd_swz(blockIdx.x, gridDim.x) * 128;
  int o0 = blockIdx.y * BN;
  int r0 = tid >> 2;
  int c8 = (tid & 3) * 8;
  f32x4 acc[MT][4] = {};
  for (int k0 = 0; k0 < CIN; k0 += 32) {
    f16x8 xa = *(const f16x8*)&Xc[(pg0 + r0) * 512 + XOFF + k0 + c8];
    f16x8 xb2 = *(const f16x8*)&Xc[(pg0 + r0 + 64) * 512 + XOFF + k0 + c8];
    f16x8 wa = *(const f16x8*)&Wh[(o0 + r0) * CIN + k0 + c8];
    f16x8 wb;
    if (BN == 128) wb = *(const f16x8*)&Wh[(o0 + r0 + 64) * CIN + k0 + c8];
    __syncthreads();
    *(f16x8*)&Xs[r0 * 40 + c8] = xa;
    *(f16x8*)&Xs[(r0 + 64) * 40 + c8] = xb2;
    *(f16x8*)&Ws[r0 * 40 + c8] = wa;
    if (BN == 128) *(f16x8*)&Ws[(r0 + 64) * 40 + c8] = wb;
    __syncthreads();
    f16x8 af[MT], bf[4];
#pragma unroll
    for (int t = 0; t < MT; ++t)
      af[t] = *(const f16x8*)&Xs[(wm * (MT * 16) + t * 16 + col) * 40 + quad * 8];
#pragma unroll
    for (int t = 0; t < 4; ++t)
      bf[t] = *(const f16x8*)&Ws[(wn * 64 + t * 16 + col) * 40 + quad * 8];
#pragma unroll
    for (int mt = 0; mt < MT; ++mt)
#pragma unroll
      for (int nt = 0; nt < 4; ++nt)
        acc[mt][nt] = __builtin_amdgcn_mfma_f32_16x16x32_f16(af[mt], bf[nt],
                                                             acc[mt][nt], 0, 0, 0);
  }
#pragma unroll
  for (int mt = 0; mt < MT; ++mt)
#pragma unroll
    for (int nt = 0; nt < 4; ++nt)
#pragma unroll
      for (int r = 0; r < 4; ++r) {
        int p = pg0 + wm * (MT * 16) + mt * 16 + quad * 4 + r;
        int ch = o0 + wn * 64 + nt * 16 + col;
        Y[p * COUT + ch] = (_Float16)acc[mt][nt][r];
      }
}

// ----- fused gather + GEMM stage 2: BM=64, grid 256, 256 thr, 4 waves ------
__global__ __launch_bounds__(256) void gemm_gather_s2(
    const _Float16* __restrict__ y, const int* __restrict__ idx,
    const float* __restrict__ g, const float* __restrict__ bb,
    const _Float16* __restrict__ Wh, _Float16* __restrict__ xcat,
    _Float16* __restrict__ Yout) {
  constexpr int CIN = 64, COUT = 128, XOFF = 64;
  constexpr int CP = CIN + 8;  // 72
  __shared__ _Float16 As[64 * CP];
  __shared__ _Float16 Ws[COUT * 40];
  int tid = threadIdx.x;
  int lane = tid & 63, w = tid >> 6;
  int col = lane & 15, quad = lane >> 4;
  int pg0 = xcd_swz(blockIdx.x, gridDim.x) * 64;
  const float inv = 1.0f / sqrtf(1.0f + 1e-5f);

  // ---- phase A: gather + minmax + bn + lrelu -> As + xcat
  constexpr int TPR = CIN / 8;  // 8
#pragma unroll
  for (int t = 0; t < (64 * TPR) / 256; ++t) {  // 2 iters
    int task = t * 256 + tid;
    int r = task / TPR;
    int c8 = task % TPR;
    int pg = pg0 + r;
    int b = pg >> 11;
    const int* ix = idx + pg * 20;
    int mm[20];
#pragma unroll
    for (int k = 0; k < 20; ++k) mm[k] = ix[k];
    int base = b * 2048 * CIN + c8 * 8;
    float mx[8], mn[8];
#pragma unroll
    for (int i = 0; i < 8; ++i) { mx[i] = -3.4e38f; mn[i] = 3.4e38f; }
#pragma unroll
    for (int k = 0; k < 20; ++k) {
      f16x8 v = *(const f16x8*)&y[base + mm[k] * CIN];
#pragma unroll
      for (int i = 0; i < 8; ++i) {
        float f = (float)v[i];
        mx[i] = fmaxf(mx[i], f);
        mn[i] = fminf(mn[i], f);
      }
    }
    f16x8 outv;
#pragma unroll
    for (int i = 0; i < 8; ++i) {
      float s = g[c8 * 8 + i] * inv;
      float vv = (s >= 0.0f) ? mx[i] : mn[i];
      outv[i] = (_Float16)lrelu(s * vv + bb[c8 * 8 + i]);
    }
    *(f16x8*)&As[r * CP + c8 * 8] = outv;
    *(f16x8*)&xcat[pg * 512 + XOFF + c8 * 8] = outv;
  }
  __syncthreads();

  // ---- phase B: GEMM (K=64, 2 steps). W staged: 128 rows x 32 halves.
  int r0 = tid >> 1;            // 0..127
  int c8b = (tid & 1) * 16;     // 0 or 16
  f32x4 acc[4][2] = {};
  for (int k0 = 0; k0 < CIN; k0 += 32) {
    f16x8 wa = *(const f16x8*)&Wh[r0 * CIN + k0 + c8b];
    f16x8 wb = *(const f16x8*)&Wh[r0 * CIN + k0 + c8b + 8];
    __syncthreads();
    *(f16x8*)&Ws[r0 * 40 + c8b] = wa;
    *(f16x8*)&Ws[r0 * 40 + c8b + 8] = wb;
    __syncthreads();
    f16x8 af[4], bf[2];
#pragma unroll
    for (int t = 0; t < 4; ++t)
      af[t] = *(const f16x8*)&As[(t * 16 + col) * CP + k0 + quad * 8];
#pragma unroll
    for (int t = 0; t < 2; ++t)
      bf[t] = *(const f16x8*)&Ws[(w * 32 + t * 16 + col) * 40 + quad * 8];
#pragma unroll
    for (int mt = 0; mt < 4; ++mt)
#pragma unroll
      for (int nt = 0; nt < 2; ++nt)
        acc[mt][nt] = __builtin_amdgcn_mfma_f32_16x16x32_f16(af[mt], bf[nt],
                                                             acc[mt][nt], 0, 0, 0);
  }
#pragma unroll
  for (int mt = 0; mt < 4; ++mt)
#pragma unroll
    for (int nt = 0; nt < 2; ++nt)
#pragma unroll
      for (int r = 0; r < 4; ++r) {
        int p = pg0 + mt * 16 + quad * 4 + r;
        int ch = w * 32 + nt * 16 + col;
        Yout[p * COUT + ch] = (_Float16)acc[mt][nt][r];
      }
}

// ----- fused gather + GEMM stage 3: BM=64, grid 256, 512 thr, 8 waves ------
__global__ __launch_bounds__(512) void gemm_gather_s3(
    const _Float16* __restrict__ y, const int* __restrict__ idx,
    const float* __restrict__ g, const float* __restrict__ bb,
    const _Float16* __restrict__ Wh, _Float16* __restrict__ xcat,
    _Float16* __restrict__ Yout) {
  constexpr int CIN = 128, COUT = 256, XOFF = 128;
  constexpr int CP = CIN + 8;  // 136
  __shared__ _Float16 As[64 * CP];
  __shared__ _Float16 Ws[COUT * 40];
  int tid = threadIdx.x;
  int lane = tid & 63, w = tid >> 6;
  int col = lane & 15, quad = lane >> 4;
  int pg0 = xcd_swz(blockIdx.x, gridDim.x) * 64;
  const float inv = 1.0f / sqrtf(1.0f + 1e-5f);

  // ---- phase A: gather + minmax + bn + lrelu -> As + xcat
  constexpr int TPR = CIN / 8;  // 16
#pragma unroll
  for (int t = 0; t < (64 * TPR) / 512; ++t) {  // 2 iters
    int task = t * 512 + tid;
    int r = task / TPR;
    int c8 = task % TPR;
    int pg = pg0 + r;
    int b = pg >> 11;
    const int* ix = idx + pg * 20;
    int mm[20];
#pragma unroll
    for (int k = 0; k < 20; ++k) mm[k] = ix[k];
    int base = b * 2048 * CIN + c8 * 8;
    float mx[8], mn[8];
#pragma unroll
    for (int i = 0; i < 8; ++i) { mx[i] = -3.4e38f; mn[i] = 3.4e38f; }
#pragma unroll
    for (int k = 0; k < 20; ++k) {
      f16x8 v = *(const f16x8*)&y[base + mm[k] * CIN];
#pragma unroll
      for (int i = 0; i < 8; ++i) {
        float f = (float)v[i];
        mx[i] = fmaxf(mx[i], f);
        mn[i] = fminf(mn[i], f);
      }
    }
    f16x8 outv;
#pragma unroll
    for (int i = 0; i < 8; ++i) {
      float s = g[c8 * 8 + i] * inv;
      float vv = (s >= 0.0f) ? mx[i] : mn[i];
      outv[i] = (_Float16)lrelu(s * vv + bb[c8 * 8 + i]);
    }
    *(f16x8*)&As[r * CP + c8 * 8] = outv;
    *(f16x8*)&xcat[pg * 512 + XOFF + c8 * 8] = outv;
  }
  __syncthreads();

  // ---- phase B: GEMM (K=128, 4 steps). W staged: 256 rows x 32 halves.
  int r0 = tid >> 1;            // 0..255
  int c8b = (tid & 1) * 16;     // 0 or 16
  f32x4 acc[4][2] = {};
  for (int k0 = 0; k0 < CIN; k0 += 32) {
    f16x8 wa = *(const f16x8*)&Wh[r0 * CIN + k0 + c8b];
    f16x8 wb = *(const f16x8*)&Wh[r0 * CIN + k0 + c8b + 8];
    __syncthreads();
    *(f16x8*)&Ws[r0 * 40 + c8b] = wa;
    *(f16x8*)&Ws[r0 * 40 + c8b + 8] = wb;
    __syncthreads();
    f16x8 af[4], bf[2];
#pragma unroll
    for (int t = 0; t < 4; ++t)
      af[t] = *(const f16x8*)&As[(t * 16 + col) * CP + k0 + quad * 8];
#pragma unroll
    for (int t = 0; t < 2; ++t)
      bf[t] = *(const f16x8*)&Ws[(w * 32 + t * 16 + col) * 40 + quad * 8];
#pragma unroll
    for (int mt = 0; mt < 4; ++mt)
#pragma unroll
      for (int nt = 0; nt < 2; ++nt)
        acc[mt][nt] = __builtin_amdgcn_mfma_f32_16x16x32_f16(af[mt], bf[nt],
                                                             acc[mt][nt], 0, 0, 0);
  }
#pragma unroll
  for (int mt = 0; mt < 4; ++mt)
#pragma unroll
    for (int nt = 0; nt < 2; ++nt)
#pragma unroll
      for (int r = 0; r < 4; ++r) {
        int p = pg0 + mt * 16 + quad * 4 + r;
        int ch = w * 32 + nt * 16 + col;
        Yout[p * COUT + ch] = (_Float16)acc[mt][nt][r];
      }
}

// ------ gemm5: 8-phase 256x256 schedule, fused BN+lrelu+pool epilogue -------
typedef const __attribute__((address_space(1))) void* gas1_t;
typedef __attribute__((address_space(3))) void* las3_t;

__device__ __forceinline__ void stage16(const _Float16* g, char* l) {
  __builtin_amdgcn_global_load_lds((gas1_t)g, (las3_t)l, 16, 0, 0);
}

__global__ __launch_bounds__(512, 2) void gemm5_kernel(
    const _Float16* __restrict__ Wh, const _Float16* __restrict__ Xc,
    const float* __restrict__ g5, const float* __restrict__ b5,
    unsigned* __restrict__ fmax, float* __restrict__ fsum) {
  __shared__ __attribute__((aligned(16))) char lds[131072];
  char* ldsc = (char*)lds;
  const int tid = threadIdx.x;
  const int lane = tid & 63, w = tid >> 6;
  const int wm = w & 1, wn = w >> 1;
  const int col = lane & 15, quad = lane >> 4;
  const int pg0 = blockIdx.x * 256;
  const int o0 = blockIdx.y * 256;

  const int so = tid << 4;
  const int sl = so ^ (((so >> 9) & 3) << 5);
  const int srow0 = sl >> 7;
  const int skc0 = (sl & 127) >> 1;

#define STG(srcp, baserow, ktile, regoff, i)                                  \
  stage16((srcp) + ((baserow) + (i) * 64 + srow0) * 512 + (ktile) * 64 + skc0,\
          ldsc + (regoff) + (i) * 8192 + (w << 10))

  const int swc = ((col >> 2) & 3) << 5;
  const int labA = (col * 128 + quad * 16) ^ swc;
  const int labB = ((wn & 1) * 8192 + col * 128 + quad * 16) ^ swc;

#define RDA(m, kk) (*(const f16x8*)(rA + ((labA ^ ((kk) << 6)) + (m) * 2048)))
#define RDB(n, kk) (*(const f16x8*)(rB + ((labB ^ ((kk) << 6)) + (n) * 2048)))

  f32x4 acc[8][4] = {};

  STG(Wh, o0, 0, 32768, 0);       STG(Wh, o0, 0, 32768, 1);        // B0
  STG(Wh, o0 + 128, 0, 49152, 0); STG(Wh, o0 + 128, 0, 49152, 1);  // B1
  STG(Xc, pg0, 0, 0, 0);          STG(Xc, pg0 + 128, 0, 16384, 0); // A i0
  STG(Xc, pg0, 0, 0, 1);          STG(Xc, pg0 + 128, 0, 16384, 1); // A i1
  asm volatile("s_waitcnt vmcnt(0)" ::: "memory");
  __builtin_amdgcn_s_barrier();

  for (int t = 0; t < 8; ++t) {
    const int nt = t + 1;
    const char* rA = ldsc + (t & 1) * 65536 + wm * 16384;
    const char* rB = ldsc + (t & 1) * 65536 + 32768 + (wn >> 1) * 16384;
    const int nreg = (nt & 1) * 65536;
    f16x8 bf[4][2];
#pragma unroll
    for (int p = 0; p < 4; ++p) {
      f16x8 a[2][2];
#pragma unroll
      for (int mm = 0; mm < 2; ++mm)
#pragma unroll
        for (int kk = 0; kk < 2; ++kk)
          a[mm][kk] = RDA(2 * p + mm, kk);
      if (p == 0) {
#pragma unroll
        for (int n = 0; n < 4; ++n)
#pragma unroll
          for (int kk = 0; kk < 2; ++kk)
            bf[n][kk] = RDB(n, kk);
      }
      if (t < 7) {
        if (p == 0) { STG(Wh, o0, nt, nreg + 32768, 0);
                      STG(Wh, o0, nt, nreg + 32768, 1); }
        if (p == 1) { STG(Wh, o0 + 128, nt, nreg + 49152, 0);
                      STG(Wh, o0 + 128, nt, nreg + 49152, 1); }
        if (p == 2) { STG(Xc, pg0, nt, nreg + 0, 0);
                      STG(Xc, pg0 + 128, nt, nreg + 16384, 0); }
        if (p == 3) { STG(Xc, pg0, nt, nreg + 0, 1);
                      STG(Xc, pg0 + 128, nt, nreg + 16384, 1); }
      }
      if (p == 1) {
        if (t < 7) { asm volatile("s_waitcnt vmcnt(4)" ::: "memory"); }
        else       { asm volatile("s_waitcnt vmcnt(0)" ::: "memory"); }
      }
      if (p == 3 && t < 7) {
        asm volatile("s_waitcnt vmcnt(2)" ::: "memory");
      }
      __builtin_amdgcn_s_barrier();
      asm volatile("s_waitcnt lgkmcnt(0)" ::: "memory");
      __builtin_amdgcn_sched_barrier(0);
      __builtin_amdgcn_s_setprio(1);
#pragma unroll
      for (int mm = 0; mm < 2; ++mm)
#pragma unroll
        for (int n = 0; n < 4; ++n)
#pragma unroll
          for (int kk = 0; kk < 2; ++kk)
            acc[2 * p + mm][n] = __builtin_amdgcn_mfma_f32_16x16x32_f16(
                a[mm][kk], bf[n][kk], acc[2 * p + mm][n], 0, 0, 0);
      __builtin_amdgcn_s_setprio(0);
      __builtin_amdgcn_s_barrier();
    }
  }
#undef STG
#undef RDA
#undef RDB

  const float inv = 1.0f / sqrtf(1.0f + 1e-5f);
  const int b = pg0 >> 11;
#pragma unroll
  for (int n = 0; n < 4; ++n) {
    int ch = o0 + wn * 64 + n * 16 + col;
    float sc = g5[ch] * inv, bi = b5[ch];
    float mx = -3.4e38f, sm = 0.f;
#pragma unroll
    for (int m = 0; m < 8; ++m)
#pragma unroll
      for (int r = 0; r < 4; ++r) {
        float v = lrelu(acc[m][n][r] * sc + bi);
        mx = fmaxf(mx, v);
        sm += v;
      }
    mx = fmaxf(mx, __shfl_xor(mx, 16, 64));
    sm += __shfl_xor(sm, 16, 64);
    mx = fmaxf(mx, __shfl_xor(mx, 32, 64));
    sm += __shfl_xor(sm, 32, 64);
    if (quad == 0) {
      atomicMax(&fmax[b * 1024 + ch], sortable_f32(mx));
      atomicAdd(&fsum[b * 1024 + ch], sm);
    }
  }
}

// ------------------------------ MLP head ------------------------------------
// l1: one block per output o; L1W row in registers, reused for all 8 batches.
__global__ __launch_bounds__(256) void l1_kernel(const unsigned* __restrict__ fmax,
                                                 const float* __restrict__ fsum,
                                                 const float* __restrict__ L1W,
                                                 const float* __restrict__ g6,
                                                 const float* __restrict__ b6,
                                                 float* __restrict__ a1) {
  __shared__ float red[4][8];
  int o = blockIdx.x;
  int tid = threadIdx.x, wv = tid >> 6;
  float4 w0 = *(const float4*)&L1W[o * 2048 + tid * 8];
  float4 w1 = *(const float4*)&L1W[o * 2048 + tid * 8 + 4];
  bool isMax = (tid < 128);
  float sb[8];
#pragma unroll
  for (int b = 0; b < 8; ++b) {
    float s;
    if (isMax) {
      uint4 a0 = *(const uint4*)&fmax[b * 1024 + tid * 8];
      uint4 a1v = *(const uint4*)&fmax[b * 1024 + tid * 8 + 4];
      s = desort_f32(a0.x) * w0.x + desort_f32(a0.y) * w0.y +
          desort_f32(a0.z) * w0.z + desort_f32(a0.w) * w0.w +
          desort_f32(a1v.x) * w1.x + desort_f32(a1v.y) * w1.y +
          desort_f32(a1v.z) * w1.z + desort_f32(a1v.w) * w1.w;
    } else {
      float4 f0 = *(const float4*)&fsum[b * 1024 + tid * 8 - 1024];
      float4 f1 = *(const float4*)&fsum[b * 1024 + tid * 8 - 1020];
      s = (f0.x * w0.x + f0.y * w0.y + f0.z * w0.z + f0.w * w0.w +
           f1.x * w1.x + f1.y * w1.y + f1.z * w1.z + f1.w * w1.w) *
          (1.0f / 2048.0f);
    }
    sb[b] = s;
  }
#pragma unroll
  for (int b = 0; b < 8; ++b)
#pragma unroll
    for (int off = 1; off < 64; off <<= 1) sb[b] += __shfl_xor(sb[b], off, 64);
  if ((tid & 63) == 0) {
#pragma unroll
    for (int b = 0; b < 8; ++b) red[wv][b] = sb[b];
  }
  __syncthreads();
  if (tid < 8) {
    float s = red[0][tid] + red[1][tid] + red[2][tid] + red[3][tid];
    float scv = g6[o] / sqrtf(1.0f + 1e-5f);
    a1[tid * 512 + o] = lrelu(s * scv + b6[o]);
  }
}

__global__ __launch_bounds__(256) void l2_kernel(const float* __restrict__ a1,
                                                 const float* __restrict__ L2W,
                                                 const float* __restrict__ L2b,
                                                 const float* __restrict__ g7,
                                                 const float* __restrict__ b7,
                                                 float* __restrict__ a2) {
  int gw = (blockIdx.x * 256 + threadIdx.x) >> 6;  // 2048 waves
  int lane = threadIdx.x & 63;
  int b = gw >> 8, o = gw & 255;
  float s = 0.f;
#pragma unroll
  for (int i = 0; i < 8; ++i) {
    int j = lane + i * 64;
    s += a1[b * 512 + j] * L2W[o * 512 + j];
  }
#pragma unroll
  for (int off = 1; off < 64; off <<= 1) s += __shfl_xor(s, off, 64);
  if (lane == 0) {
    float v = s + L2b[o];
    float scv = g7[o] / sqrtf(1.0f + 1e-5f);
    a2[b * 256 + o] = lrelu(v * scv + b7[o]);
  }
}

__global__ __launch_bounds__(256) void l3_kernel(const float* __restrict__ a2,
                                                 const float* __restrict__ L3W,
                                                 const float* __restrict__ L3b,
                                                 float* __restrict__ out) {
  int gw = (blockIdx.x * 256 + threadIdx.x) >> 6;  // 320 waves
  int lane = threadIdx.x & 63;
  int b = gw / 40, o = gw % 40;
  float s = 0.f;
#pragma unroll
  for (int i = 0; i < 4; ++i) {
    int j = lane + i * 64;
    s += a2[b * 256 + j] * L3W[o * 256 + j];
  }
#pragma unroll
  for (int off = 1; off < 64; off <<= 1) s += __shfl_xor(s, off, 64);
  if (lane == 0) out[b * 40 + o] = s + L3b[o];
}

// ---------------------------------------------------------------------------
extern "C" void kernel_launch(void* const* d_in, const int* in_sizes, int n_in,
                              void* d_out, int out_size, void* d_ws, size_t ws_size,
                              hipStream_t stream) {
  const float* x = (const float*)d_in[0];
  const float* W1 = (const float*)d_in[1];
  const float* W2 = (const float*)d_in[2];
  const float* W3 = (const float*)d_in[3];
  const float* W4 = (const float*)d_in[4];
  const float* W5 = (const float*)d_in[5];
  const float* g1 = (const float*)d_in[6];  const float* b1 = (const float*)d_in[7];
  const float* g2 = (const float*)d_in[8];  const float* b2 = (const float*)d_in[9];
  const float* g3 = (const float*)d_in[10]; const float* b3 = (const float*)d_in[11];
  const float* g4 = (const float*)d_in[12]; const float* b4 = (const float*)d_in[13];
  const float* g5 = (const float*)d_in[14]; const float* b5 = (const float*)d_in[15];
  const float* g6 = (const float*)d_in[16]; const float* b6 = (const float*)d_in[17];
  const float* g7 = (const float*)d_in[18]; const float* b7 = (const float*)d_in[19];
  const float* L1W = (const float*)d_in[20];
  const float* L2W = (const float*)d_in[21];
  const float* L2b = (const float*)d_in[22];
  const float* L3W = (const float*)d_in[23];
  const float* L3b = (const float*)d_in[24];

  char* w = (char*)d_ws;
  int* idxb = (int*)(w + WS_IDX);
  _Float16* y16 = (_Float16*)(w + WS_Y16);
  _Float16* y16b = (_Float16*)(w + WS_Y16B);
  _Float16* xcat16 = (_Float16*)(w + WS_XCAT16);
  _Float16* w16 = (_Float16*)(w + WS_W16);
  unsigned* fmax = (unsigned*)(w + WS_FMAX);
  float* fsum = (float*)(w + WS_FSUM);
  float* a1 = (float*)(w + WS_A1);
  float* a2 = (float*)(w + WS_A2);

  knn_prep_kernel<<<2191, 512, 0, stream>>>(x, W1, g1, b1, W2, W3, W4, W5,
                                            w16, fmax, idxb, xcat16);
  gemm_mfma<64, 64, 0><<<dim3(128, 1), 256, 0, stream>>>(w16, xcat16, y16);
  // fused gmax1 + gemm2 (BM=64, grid 256): y16(64ch) -> xcat[64:128] + y16b
  gemm_gather_s2<<<256, 256, 0, stream>>>(
      y16, idxb, g2, b2, w16 + 4096, xcat16, y16b);
  // fused gmax2 + gemm3 (BM=64, grid 256): y16b -> xcat[128:256] + y16(256ch)
  gemm_gather_s3<<<256, 512, 0, stream>>>(
      y16b, idxb, g3, b3, w16 + 12288, xcat16, y16);
  gmax_kernel<256, 256><<<2048, 256, 0, stream>>>(y16, idxb, g4, b4, xcat16);
  gemm5_kernel<<<dim3(64, 4), 512, 0, stream>>>(w16 + 45056, xcat16, g5, b5, fmax, fsum);
  l1_kernel<<<512, 256, 0, stream>>>(fmax, fsum, L1W, g6, b6, a1);
  l2_kernel<<<512, 256, 0, stream>>>(a1, L2W, L2b, g7, b7, a2);
  l3_kernel<<<80, 256, 0, stream>>>(a2, L3W, L3b, (float*)d_out);
}

// Round 12
// 202.126 us; speedup vs baseline: 1.0817x; 1.0817x over previous
//
#include <hip/hip_runtime.h>
#include <math.h>

// ---------------------------------------------------------------------------
// DGCNN-style network, B=8, N=2048, K=20, eval-mode BN.
// Round 23: knn reverted BYTE-EXACT to r18 (best measured: 203.55 total).
// knn experiment ledger: r20 recompute (-VGPR, +VALU) = +9us WORSE;
// r22 float4 |p|^2 precompute = +14us WORSE (occ 20%, r10's note was right).
// r18 config (float3, keys[32] cache, ballot compaction, 512thr 1q/wave)
// is the local optimum: instruction-issue-bound, both "more occupancy" and
// "fewer LDS bytes" directions lose. DO NOT TOUCH knn further.
// New this round: gemm1 BM 128->64 (grid 256, LDS 10KB) - the 134-MFLOP
// latency-bound GEMM previously covered only 128 of 256 CUs. Bit-identical.
// r19: BM=64 fused gather-GEMMs. r17: batch-aligned XCD swizzle (-8us).
// r16: single-gather + l1 reuse (-5.6us). r13: gemm5 8-phase m201 (-10us).
// Trick (verified r1-r10): max_k lrelu(bn(h)) == lrelu(bn(max_k h)) for bn
// scale>=0, min_k when scale<0 -> gather reduces max AND min of pre-BN y.
// ---------------------------------------------------------------------------

#define WS_IDX      0            // int[16384*20]            1,310,720 B
#define WS_Y16      1310720     // half[16384*256]          8,388,608 B  (y16a)
#define WS_XCAT16   9699328     // half[16384*512]          16,777,216 B
#define WS_W16      26476544    // half[569344]             1,138,688 B
#define WS_FMAX     27615232    // uint[8*1024]             32,768 B
#define WS_FSUM     27648000    // float[8*1024]            32,768 B
#define WS_A1       27680768    // float[8*512]             16,384 B
#define WS_A2       27697152    // float[8*256]             8,192 B
#define WS_Y16B     27705344    // half[16384*128]          4,194,304 B  (y16b)
// total ~31.9 MB

typedef _Float16 f16x8 __attribute__((ext_vector_type(8)));
typedef float f32x4 __attribute__((ext_vector_type(4)));

struct F3 { float x, y, z; };

__device__ __forceinline__ float lrelu(float v) { return (v >= 0.f) ? v : 0.2f * v; }
__device__ __forceinline__ unsigned sortable_f32(float f) {
  unsigned b = __float_as_uint(f);
  return b ^ (((unsigned)((int)b >> 31)) | 0x80000000u);
}
__device__ __forceinline__ float desort_f32(unsigned u) {
  unsigned b = (u & 0x80000000u) ? (u ^ 0x80000000u) : ~u;
  return __uint_as_float(b);
}
// batch-aligned XCD swizzle: i%8 -> XCD under round-robin dispatch; with
// per-batch chunk = nwg/8, batch(bid) = i%8. Bijective for nwg%8==0.
__device__ __forceinline__ int xcd_swz(int i, int nwg) {
  return (i & 7) * (nwg >> 3) + (i >> 3);
}

// --------------------- KNN + edge1 + prep (one dispatch) --------------------
// EXACT r18 configuration (best measured). 512 thr, 8 waves, 1 query/wave.
// pts as float3 in LDS; pass1 caches 32 sortable keys/lane in regs +
// lane-max -> 16-iter ballot bisection -> T; pass2 ballot-prefix compaction
// (no atomics); 64-lane bitonic sort == exact jax.lax.top_k tie-break;
// C>60 -> exact slow path from cached keys. Then edge1 -> xcat[:,0:64].
// Blocks [2048,2191): W2..W5 -> fp16 w16; zero fmax/fsum.
__global__ __launch_bounds__(512) void knn_prep_kernel(
    const float* __restrict__ x, const float* __restrict__ W1,
    const float* __restrict__ g1, const float* __restrict__ b1,
    const float* __restrict__ W2, const float* __restrict__ W3,
    const float* __restrict__ W4, const float* __restrict__ W5,
    _Float16* __restrict__ w16, unsigned* __restrict__ fzero,
    int* __restrict__ idxo, _Float16* __restrict__ xcat) {
  __shared__ F3 pts_s[2048];                    // 24576 B
  __shared__ unsigned long long cand_s[8][60];  // 3840 B
  __shared__ int sel_s[8][20];                  // 640 B
  int tid = threadIdx.x;

  if (blockIdx.x >= 2048) {  // ---- prep branch: 143 blocks x 4096 items ----
    int bid = blockIdx.x - 2048;
#pragma unroll
    for (int t = 0; t < 8; ++t) {
      int i = bid * 4096 + t * 512 + tid;
      if (i < 4096) w16[i] = (_Float16)W2[i];
      else if (i < 12288) w16[i] = (_Float16)W3[i - 4096];
      else if (i < 45056) w16[i] = (_Float16)W4[i - 12288];
      else if (i < 569344) w16[i] = (_Float16)W5[i - 45056];
      else fzero[i - 569344] = 0u;  // fmax (sortable 0 < any finite) + fsum
    }
    return;
  }

  int wv = tid >> 6, lane = tid & 63;  // wv 0..7, one query per wave
  int qbase = blockIdx.x * 8;
  int b = qbase >> 11;
  int nbase = qbase & 2047;
  const float* xb = x + b * 6144;
#pragma unroll
  for (int i = 0; i < 4; ++i) {
    int m = tid + i * 512;
    F3 p; p.x = xb[m]; p.y = xb[2048 + m]; p.z = xb[4096 + m];
    pts_s[m] = p;
  }
  __syncthreads();

  F3 q = pts_s[nbase + wv];
  float qw = q.x * q.x + q.y * q.y + q.z * q.z;
  unsigned keys[32];
  unsigned lmax = 0u;
#pragma unroll
  for (int j = 0; j < 32; ++j) {
    F3 p = pts_s[j * 64 + lane];
    float pw = p.x * p.x + p.y * p.y + p.z * p.z;
    float nd = 2.0f * (q.x * p.x + q.y * p.y + q.z * p.z) - qw - pw;
    unsigned key = sortable_f32(nd);
    keys[j] = key;
    lmax = (key > lmax) ? key : lmax;
  }
  unsigned lo = 0u, hi = 0x8001u;
  for (int it = 0; it < 16; ++it) {
    unsigned mid = (lo + hi + 1) >> 1;
    int cnt = __popcll(__ballot(lmax >= (mid << 16)));
    if (cnt >= 20) lo = mid; else hi = mid;
  }
  unsigned T = lo << 16;
  // ballot-prefix compaction (no atomics); cnt is wave-uniform
  unsigned cnt = 0u;
  unsigned long long below = (1ull << lane) - 1ull;
#pragma unroll
  for (int j = 0; j < 32; ++j) {
    int m = j * 64 + lane;
    bool pass = keys[j] >= T;
    unsigned long long mask = __ballot(pass);
    if (pass) {
      unsigned pos = cnt + (unsigned)__popcll(mask & below);
      if (pos < 60)
        cand_s[wv][pos] =
            (((unsigned long long)keys[j]) << 32) | (unsigned)(2047 - m);
    }
    cnt += (unsigned)__popcll(mask);
  }

  int row = qbase + wv;
  int outb = row * 20;
  unsigned C = cnt;  // wave-uniform
  if (C <= 60) {
    unsigned long long v = (lane < (int)C) ? ~cand_s[wv][lane] : ~0ull;
#pragma unroll
    for (int k = 2; k <= 64; k <<= 1) {
#pragma unroll
      for (int jj = k >> 1; jj > 0; jj >>= 1) {
        unsigned long long o = __shfl_xor(v, jj, 64);
        bool lower = (lane & jj) == 0;
        bool up = (lane & k) == 0;
        bool takeMin = (lower == up);
        bool sw = takeMin ? (o < v) : (o > v);
        v = sw ? o : v;
      }
    }
    if (lane < 20) {
      unsigned long long pack = ~v;
      int m = 2047 - (int)(pack & 0xFFFFFFFFu);
      idxo[outb + lane] = m;
      sel_s[wv][lane] = m;
    }
  } else {
    unsigned long long prev = ~0ull;
    for (int r = 0; r < 20; ++r) {
      unsigned long long best = 0ull;
#pragma unroll
      for (int j = 0; j < 32; ++j) {
        int m = j * 64 + lane;
        unsigned long long pk =
            (((unsigned long long)keys[j]) << 32) | (unsigned)(2047 - m);
        bool ok = (pk < prev) & (pk > best);
        best = ok ? pk : best;
      }
#pragma unroll
      for (int off = 1; off < 64; off <<= 1) {
        unsigned long long o = __shfl_xor(best, off, 64);
        best = (o > best) ? o : best;
      }
      int m = 2047 - (int)(best & 0xFFFFFFFFu);
      if (lane == 0) { idxo[outb + r] = m; sel_s[wv][r] = m; }
      prev = best;
    }
  }

  float w0 = W1[lane * 3 + 0], w1 = W1[lane * 3 + 1], w2 = W1[lane * 3 + 2];
  float inv = 1.0f / sqrtf(1.0f + 1e-5f);
  float sc = g1[lane] * inv, bi = b1[lane];
  {
    float mx = -3.4e38f, mn = 3.4e38f;
#pragma unroll
    for (int k = 0; k < 20; ++k) {
      F3 p = pts_s[sel_s[wv][k]];
      float v = w0 * p.x + w1 * p.y + w2 * p.z;
      mx = fmaxf(mx, v);
      mn = fminf(mn, v);
    }
    float v = (sc >= 0.0f) ? mx : mn;
    xcat[row * 512 + lane] = (_Float16)lrelu(sc * v + bi);
  }
}

// --------------- gather max/min + BN + lrelu -> fp16 (f16x8) ----------------
template <int C, int COFF>
__global__ __launch_bounds__(256) void gmax_kernel(const _Float16* __restrict__ y,
                                                   const int* __restrict__ idx,
                                                   const float* __restrict__ g,
                                                   const float* __restrict__ bb,
                                                   _Float16* __restrict__ xcat) {
  constexpr int TP = C / 8;
  int bxs = xcd_swz(blockIdx.x, gridDim.x);
  int e = bxs * 256 + threadIdx.x;
  int c8 = e & (TP - 1);
  int pg = e / TP;
  int b = pg >> 11;
  const int* ix = idx + pg * 20;
  int mm[20];
#pragma unroll
  for (int k = 0; k < 20; ++k) mm[k] = ix[k];
  int base = b * 2048 * C + c8 * 8;
  float mx[8], mn[8];
#pragma unroll
  for (int i = 0; i < 8; ++i) { mx[i] = -3.4e38f; mn[i] = 3.4e38f; }
#pragma unroll
  for (int k = 0; k < 20; ++k) {
    f16x8 v = *(const f16x8*)&y[base + mm[k] * C];
#pragma unroll
    for (int i = 0; i < 8; ++i) {
      float f = (float)v[i];
      mx[i] = fmaxf(mx[i], f);
      mn[i] = fminf(mn[i], f);
    }
  }
  float inv = 1.0f / sqrtf(1.0f + 1e-5f);
  f16x8 outv;
#pragma unroll
  for (int i = 0; i < 8; ++i) {
    float s = g[c8 * 8 + i] * inv;
    float v = (s >= 0.0f) ? mx[i] : mn[i];
    outv[i] = (_Float16)lrelu(s * v + bb[c8 * 8 + i]);
  }
  *(f16x8*)&xcat[pg * 512 + COFF + c8 * 8] = outv;
}

// ------------- gemm1: BM=64 BN=64 K=64, grid 256, 4 waves x (16x64) --------
__global__ __launch_bounds__(256) void gemm1_kernel(
    const _Float16* __restrict__ Wh, const _Float16* __restrict__ Xc,
    _Float16* __restrict__ Y) {
  __shared__ _Float16 Xs[64 * 40];
  __shared__ _Float16 Ws[64 * 40];
  int tid = threadIdx.x;
  int lane = tid & 63, w = tid >> 6;
  int col = lane & 15, quad = lane >> 4;
  int pg0 = xcd_swz(blockIdx.x, gridDim.x) * 64;
  int r0 = tid >> 2;
  int c8 = (tid & 3) * 8;
  f32x4 acc[4] = {};
  for (int k0 = 0; k0 < 64; k0 += 32) {
    f16x8 xa = *(const f16x8*)&Xc[(pg0 + r0) * 512 + k0 + c8];
    f16x8 wa = *(const f16x8*)&Wh[r0 * 64 + k0 + c8];
    __syncthreads();
    *(f16x8*)&Xs[r0 * 40 + c8] = xa;
    *(f16x8*)&Ws[r0 * 40 + c8] = wa;
    __syncthreads();
    f16x8 af = *(const f16x8*)&Xs[(w * 16 + col) * 40 + quad * 8];
    f16x8 bf[4];
#pragma unroll
    for (int t = 0; t < 4; ++t)
      bf[t] = *(const f16x8*)&Ws[(t * 16 + col) * 40 + quad * 8];
#pragma unroll
    for (int nt = 0; nt < 4; ++nt)
      acc[nt] = __builtin_amdgcn_mfma_f32_16x16x32_f16(af, bf[nt], acc[nt], 0, 0, 0);
  }
#pragma unroll
  for (int nt = 0; nt < 4; ++nt)
#pragma unroll
    for (int r = 0; r < 4; ++r) {
      int p = pg0 + w * 16 + quad * 4 + r;
      int ch = nt * 16 + col;
      Y[p * 64 + ch] = (_Float16)acc[nt][r];
    }
}

// ----- fused gather + GEMM stage 2: BM=64, grid 256, 256 thr, 4 waves ------
__global__ __launch_bounds__(256) void gemm_gather_s2(
    const _Float16* __restrict__ y, const int* __restrict__ idx,
    const float* __restrict__ g, const float* __restrict__ bb,
    const _Float16* __restrict__ Wh, _Float16* __restrict__ xcat,
    _Float16* __restrict__ Yout) {
  constexpr int CIN = 64, COUT = 128, XOFF = 64;
  constexpr int CP = CIN + 8;  // 72
  __shared__ _Float16 As[64 * CP];
  __shared__ _Float16 Ws[COUT * 40];
  int tid = threadIdx.x;
  int lane = tid & 63, w = tid >> 6;
  int col = lane & 15, quad = lane >> 4;
  int pg0 = xcd_swz(blockIdx.x, gridDim.x) * 64;
  const float inv = 1.0f / sqrtf(1.0f + 1e-5f);

  // ---- phase A: gather + minmax + bn + lrelu -> As + xcat
  constexpr int TPR = CIN / 8;  // 8
#pragma unroll
  for (int t = 0; t < (64 * TPR) / 256; ++t) {  // 2 iters
    int task = t * 256 + tid;
    int r = task / TPR;
    int c8 = task % TPR;
    int pg = pg0 + r;
    int b = pg >> 11;
    const int* ix = idx + pg * 20;
    int mm[20];
#pragma unroll
    for (int k = 0; k < 20; ++k) mm[k] = ix[k];
    int base = b * 2048 * CIN + c8 * 8;
    float mx[8], mn[8];
#pragma unroll
    for (int i = 0; i < 8; ++i) { mx[i] = -3.4e38f; mn[i] = 3.4e38f; }
#pragma unroll
    for (int k = 0; k < 20; ++k) {
      f16x8 v = *(const f16x8*)&y[base + mm[k] * CIN];
#pragma unroll
      for (int i = 0; i < 8; ++i) {
        float f = (float)v[i];
        mx[i] = fmaxf(mx[i], f);
        mn[i] = fminf(mn[i], f);
      }
    }
    f16x8 outv;
#pragma unroll
    for (int i = 0; i < 8; ++i) {
      float s = g[c8 * 8 + i] * inv;
      float vv = (s >= 0.0f) ? mx[i] : mn[i];
      outv[i] = (_Float16)lrelu(s * vv + bb[c8 * 8 + i]);
    }
    *(f16x8*)&As[r * CP + c8 * 8] = outv;
    *(f16x8*)&xcat[pg * 512 + XOFF + c8 * 8] = outv;
  }
  __syncthreads();

  // ---- phase B: GEMM (K=64, 2 steps). W staged: 128 rows x 32 halves.
  int r0 = tid >> 1;            // 0..127
  int c8b = (tid & 1) * 16;     // 0 or 16
  f32x4 acc[4][2] = {};
  for (int k0 = 0; k0 < CIN; k0 += 32) {
    f16x8 wa = *(const f16x8*)&Wh[r0 * CIN + k0 + c8b];
    f16x8 wb = *(const f16x8*)&Wh[r0 * CIN + k0 + c8b + 8];
    __syncthreads();
    *(f16x8*)&Ws[r0 * 40 + c8b] = wa;
    *(f16x8*)&Ws[r0 * 40 + c8b + 8] = wb;
    __syncthreads();
    f16x8 af[4], bf[2];
#pragma unroll
    for (int t = 0; t < 4; ++t)
      af[t] = *(const f16x8*)&As[(t * 16 + col) * CP + k0 + quad * 8];
#pragma unroll
    for (int t = 0; t < 2; ++t)
      bf[t] = *(const f16x8*)&Ws[(w * 32 + t * 16 + col) * 40 + quad * 8];
#pragma unroll
    for (int mt = 0; mt < 4; ++mt)
#pragma unroll
      for (int nt = 0; nt < 2; ++nt)
        acc[mt][nt] = __builtin_amdgcn_mfma_f32_16x16x32_f16(af[mt], bf[nt],
                                                             acc[mt][nt], 0, 0, 0);
  }
#pragma unroll
  for (int mt = 0; mt < 4; ++mt)
#pragma unroll
    for (int nt = 0; nt < 2; ++nt)
#pragma unroll
      for (int r = 0; r < 4; ++r) {
        int p = pg0 + mt * 16 + quad * 4 + r;
        int ch = w * 32 + nt * 16 + col;
        Yout[p * COUT + ch] = (_Float16)acc[mt][nt][r];
      }
}

// ----- fused gather + GEMM stage 3: BM=64, grid 256, 512 thr, 8 waves ------
__global__ __launch_bounds__(512) void gemm_gather_s3(
    const _Float16* __restrict__ y, const int* __restrict__ idx,
    const float* __restrict__ g, const float* __restrict__ bb,
    const _Float16* __restrict__ Wh, _Float16* __restrict__ xcat,
    _Float16* __restrict__ Yout) {
  constexpr int CIN = 128, COUT = 256, XOFF = 128;
  constexpr int CP = CIN + 8;  // 136
  __shared__ _Float16 As[64 * CP];
  __shared__ _Float16 Ws[COUT * 40];
  int tid = threadIdx.x;
  int lane = tid & 63, w = tid >> 6;
  int col = lane & 15, quad = lane >> 4;
  int pg0 = xcd_swz(blockIdx.x, gridDim.x) * 64;
  const float inv = 1.0f / sqrtf(1.0f + 1e-5f);

  // ---- phase A: gather + minmax + bn + lrelu -> As + xcat
  constexpr int TPR = CIN / 8;  // 16
#pragma unroll
  for (int t = 0; t < (64 * TPR) / 512; ++t) {  // 2 iters
    int task = t * 512 + tid;
    int r = task / TPR;
    int c8 = task % TPR;
    int pg = pg0 + r;
    int b = pg >> 11;
    const int* ix = idx + pg * 20;
    int mm[20];
#pragma unroll
    for (int k = 0; k < 20; ++k) mm[k] = ix[k];
    int base = b * 2048 * CIN + c8 * 8;
    float mx[8], mn[8];
#pragma unroll
    for (int i = 0; i < 8; ++i) { mx[i] = -3.4e38f; mn[i] = 3.4e38f; }
#pragma unroll
    for (int k = 0; k < 20; ++k) {
      f16x8 v = *(const f16x8*)&y[base + mm[k] * CIN];
#pragma unroll
      for (int i = 0; i < 8; ++i) {
        float f = (float)v[i];
        mx[i] = fmaxf(mx[i], f);
        mn[i] = fminf(mn[i], f);
      }
    }
    f16x8 outv;
#pragma unroll
    for (int i = 0; i < 8; ++i) {
      float s = g[c8 * 8 + i] * inv;
      float vv = (s >= 0.0f) ? mx[i] : mn[i];
      outv[i] = (_Float16)lrelu(s * vv + bb[c8 * 8 + i]);
    }
    *(f16x8*)&As[r * CP + c8 * 8] = outv;
    *(f16x8*)&xcat[pg * 512 + XOFF + c8 * 8] = outv;
  }
  __syncthreads();

  // ---- phase B: GEMM (K=128, 4 steps). W staged: 256 rows x 32 halves.
  int r0 = tid >> 1;            // 0..255
  int c8b = (tid & 1) * 16;     // 0 or 16
  f32x4 acc[4][2] = {};
  for (int k0 = 0; k0 < CIN; k0 += 32) {
    f16x8 wa = *(const f16x8*)&Wh[r0 * CIN + k0 + c8b];
    f16x8 wb = *(const f16x8*)&Wh[r0 * CIN + k0 + c8b + 8];
    __syncthreads();
    *(f16x8*)&Ws[r0 * 40 + c8b] = wa;
    *(f16x8*)&Ws[r0 * 40 + c8b + 8] = wb;
    __syncthreads();
    f16x8 af[4], bf[2];
#pragma unroll
    for (int t = 0; t < 4; ++t)
      af[t] = *(const f16x8*)&As[(t * 16 + col) * CP + k0 + quad * 8];
#pragma unroll
    for (int t = 0; t < 2; ++t)
      bf[t] = *(const f16x8*)&Ws[(w * 32 + t * 16 + col) * 40 + quad * 8];
#pragma unroll
    for (int mt = 0; mt < 4; ++mt)
#pragma unroll
      for (int nt = 0; nt < 2; ++nt)
        acc[mt][nt] = __builtin_amdgcn_mfma_f32_16x16x32_f16(af[mt], bf[nt],
                                                             acc[mt][nt], 0, 0, 0);
  }
#pragma unroll
  for (int mt = 0; mt < 4; ++mt)
#pragma unroll
    for (int nt = 0; nt < 2; ++nt)
#pragma unroll
      for (int r = 0; r < 4; ++r) {
        int p = pg0 + mt * 16 + quad * 4 + r;
        int ch = w * 32 + nt * 16 + col;
        Yout[p * COUT + ch] = (_Float16)acc[mt][nt][r];
      }
}

// ------ gemm5: 8-phase 256x256 schedule, fused BN+lrelu+pool epilogue -------
typedef const __attribute__((address_space(1))) void* gas1_t;
typedef __attribute__((address_space(3))) void* las3_t;

__device__ __forceinline__ void stage16(const _Float16* g, char* l) {
  __builtin_amdgcn_global_load_lds((gas1_t)g, (las3_t)l, 16, 0, 0);
}

__global__ __launch_bounds__(512, 2) void gemm5_kernel(
    const _Float16* __restrict__ Wh, const _Float16* __restrict__ Xc,
    const float* __restrict__ g5, const float* __restrict__ b5,
    unsigned* __restrict__ fmax, float* __restrict__ fsum) {
  __shared__ __attribute__((aligned(16))) char lds[131072];
  char* ldsc = (char*)lds;
  const int tid = threadIdx.x;
  const int lane = tid & 63, w = tid >> 6;
  const int wm = w & 1, wn = w >> 1;
  const int col = lane & 15, quad = lane >> 4;
  const int pg0 = blockIdx.x * 256;
  const int o0 = blockIdx.y * 256;

  const int so = tid << 4;
  const int sl = so ^ (((so >> 9) & 3) << 5);
  const int srow0 = sl >> 7;
  const int skc0 = (sl & 127) >> 1;

#define STG(srcp, baserow, ktile, regoff, i)                                  \
  stage16((srcp) + ((baserow) + (i) * 64 + srow0) * 512 + (ktile) * 64 + skc0,\
          ldsc + (regoff) + (i) * 8192 + (w << 10))

  const int swc = ((col >> 2) & 3) << 5;
  const int labA = (col * 128 + quad * 16) ^ swc;
  const int labB = ((wn & 1) * 8192 + col * 128 + quad * 16) ^ swc;

#define RDA(m, kk) (*(const f16x8*)(rA + ((labA ^ ((kk) << 6)) + (m) * 2048)))
#define RDB(n, kk) (*(const f16x8*)(rB + ((labB ^ ((kk) << 6)) + (n) * 2048)))

  f32x4 acc[8][4] = {};

  STG(Wh, o0, 0, 32768, 0);       STG(Wh, o0, 0, 32768, 1);        // B0
  STG(Wh, o0 + 128, 0, 49152, 0); STG(Wh, o0 + 128, 0, 49152, 1);  // B1
  STG(Xc, pg0, 0, 0, 0);          STG(Xc, pg0 + 128, 0, 16384, 0); // A i0
  STG(Xc, pg0, 0, 0, 1);          STG(Xc, pg0 + 128, 0, 16384, 1); // A i1
  asm volatile("s_waitcnt vmcnt(0)" ::: "memory");
  __builtin_amdgcn_s_barrier();

  for (int t = 0; t < 8; ++t) {
    const int nt = t + 1;
    const char* rA = ldsc + (t & 1) * 65536 + wm * 16384;
    const char* rB = ldsc + (t & 1) * 65536 + 32768 + (wn >> 1) * 16384;
    const int nreg = (nt & 1) * 65536;
    f16x8 bf[4][2];
#pragma unroll
    for (int p = 0; p < 4; ++p) {
      f16x8 a[2][2];
#pragma unroll
      for (int mm = 0; mm < 2; ++mm)
#pragma unroll
        for (int kk = 0; kk < 2; ++kk)
          a[mm][kk] = RDA(2 * p + mm, kk);
      if (p == 0) {
#pragma unroll
        for (int n = 0; n < 4; ++n)
#pragma unroll
          for (int kk = 0; kk < 2; ++kk)
            bf[n][kk] = RDB(n, kk);
      }
      if (t < 7) {
        if (p == 0) { STG(Wh, o0, nt, nreg + 32768, 0);
                      STG(Wh, o0, nt, nreg + 32768, 1); }
        if (p == 1) { STG(Wh, o0 + 128, nt, nreg + 49152, 0);
                      STG(Wh, o0 + 128, nt, nreg + 49152, 1); }
        if (p == 2) { STG(Xc, pg0, nt, nreg + 0, 0);
                      STG(Xc, pg0 + 128, nt, nreg + 16384, 0); }
        if (p == 3) { STG(Xc, pg0, nt, nreg + 0, 1);
                      STG(Xc, pg0 + 128, nt, nreg + 16384, 1); }
      }
      if (p == 1) {
        if (t < 7) { asm volatile("s_waitcnt vmcnt(4)" ::: "memory"); }
        else       { asm volatile("s_waitcnt vmcnt(0)" ::: "memory"); }
      }
      if (p == 3 && t < 7) {
        asm volatile("s_waitcnt vmcnt(2)" ::: "memory");
      }
      __builtin_amdgcn_s_barrier();
      asm volatile("s_waitcnt lgkmcnt(0)" ::: "memory");
      __builtin_amdgcn_sched_barrier(0);
      __builtin_amdgcn_s_setprio(1);
#pragma unroll
      for (int mm = 0; mm < 2; ++mm)
#pragma unroll
        for (int n = 0; n < 4; ++n)
#pragma unroll
          for (int kk = 0; kk < 2; ++kk)
            acc[2 * p + mm][n] = __builtin_amdgcn_mfma_f32_16x16x32_f16(
                a[mm][kk], bf[n][kk], acc[2 * p + mm][n], 0, 0, 0);
      __builtin_amdgcn_s_setprio(0);
      __builtin_amdgcn_s_barrier();
    }
  }
#undef STG
#undef RDA
#undef RDB

  const float inv = 1.0f / sqrtf(1.0f + 1e-5f);
  const int b = pg0 >> 11;
#pragma unroll
  for (int n = 0; n < 4; ++n) {
    int ch = o0 + wn * 64 + n * 16 + col;
    float sc = g5[ch] * inv, bi = b5[ch];
    float mx = -3.4e38f, sm = 0.f;
#pragma unroll
    for (int m = 0; m < 8; ++m)
#pragma unroll
      for (int r = 0; r < 4; ++r) {
        float v = lrelu(acc[m][n][r] * sc + bi);
        mx = fmaxf(mx, v);
        sm += v;
      }
    mx = fmaxf(mx, __shfl_xor(mx, 16, 64));
    sm += __shfl_xor(sm, 16, 64);
    mx = fmaxf(mx, __shfl_xor(mx, 32, 64));
    sm += __shfl_xor(sm, 32, 64);
    if (quad == 0) {
      atomicMax(&fmax[b * 1024 + ch], sortable_f32(mx));
      atomicAdd(&fsum[b * 1024 + ch], sm);
    }
  }
}

// ------------------------------ MLP head ------------------------------------
// l1: one block per output o; L1W row in registers, reused for all 8 batches.
__global__ __launch_bounds__(256) void l1_kernel(const unsigned* __restrict__ fmax,
                                                 const float* __restrict__ fsum,
                                                 const float* __restrict__ L1W,
                                                 const float* __restrict__ g6,
                                                 const float* __restrict__ b6,
                                                 float* __restrict__ a1) {
  __shared__ float red[4][8];
  int o = blockIdx.x;
  int tid = threadIdx.x, wv = tid >> 6;
  float4 w0 = *(const float4*)&L1W[o * 2048 + tid * 8];
  float4 w1 = *(const float4*)&L1W[o * 2048 + tid * 8 + 4];
  bool isMax = (tid < 128);
  float sb[8];
#pragma unroll
  for (int b = 0; b < 8; ++b) {
    float s;
    if (isMax) {
      uint4 a0 = *(const uint4*)&fmax[b * 1024 + tid * 8];
      uint4 a1v = *(const uint4*)&fmax[b * 1024 + tid * 8 + 4];
      s = desort_f32(a0.x) * w0.x + desort_f32(a0.y) * w0.y +
          desort_f32(a0.z) * w0.z + desort_f32(a0.w) * w0.w +
          desort_f32(a1v.x) * w1.x + desort_f32(a1v.y) * w1.y +
          desort_f32(a1v.z) * w1.z + desort_f32(a1v.w) * w1.w;
    } else {
      float4 f0 = *(const float4*)&fsum[b * 1024 + tid * 8 - 1024];
      float4 f1 = *(const float4*)&fsum[b * 1024 + tid * 8 - 1020];
      s = (f0.x * w0.x + f0.y * w0.y + f0.z * w0.z + f0.w * w0.w +
           f1.x * w1.x + f1.y * w1.y + f1.z * w1.z + f1.w * w1.w) *
          (1.0f / 2048.0f);
    }
    sb[b] = s;
  }
#pragma unroll
  for (int b = 0; b < 8; ++b)
#pragma unroll
    for (int off = 1; off < 64; off <<= 1) sb[b] += __shfl_xor(sb[b], off, 64);
  if ((tid & 63) == 0) {
#pragma unroll
    for (int b = 0; b < 8; ++b) red[wv][b] = sb[b];
  }
  __syncthreads();
  if (tid < 8) {
    float s = red[0][tid] + red[1][tid] + red[2][tid] + red[3][tid];
    float scv = g6[o] / sqrtf(1.0f + 1e-5f);
    a1[tid * 512 + o] = lrelu(s * scv + b6[o]);
  }
}

__global__ __launch_bounds__(256) void l2_kernel(const float* __restrict__ a1,
                                                 const float* __restrict__ L2W,
                                                 const float* __restrict__ L2b,
                                                 const float* __restrict__ g7,
                                                 const float* __restrict__ b7,
                                                 float* __restrict__ a2) {
  int gw = (blockIdx.x * 256 + threadIdx.x) >> 6;  // 2048 waves
  int lane = threadIdx.x & 63;
  int b = gw >> 8, o = gw & 255;
  float s = 0.f;
#pragma unroll
  for (int i = 0; i < 8; ++i) {
    int j = lane + i * 64;
    s += a1[b * 512 + j] * L2W[o * 512 + j];
  }
#pragma unroll
  for (int off = 1; off < 64; off <<= 1) s += __shfl_xor(s, off, 64);
  if (lane == 0) {
    float v = s + L2b[o];
    float scv = g7[o] / sqrtf(1.0f + 1e-5f);
    a2[b * 256 + o] = lrelu(v * scv + b7[o]);
  }
}

__global__ __launch_bounds__(256) void l3_kernel(const float* __restrict__ a2,
                                                 const float* __restrict__ L3W,
                                                 const float* __restrict__ L3b,
                                                 float* __restrict__ out) {
  int gw = (blockIdx.x * 256 + threadIdx.x) >> 6;  // 320 waves
  int lane = threadIdx.x & 63;
  int b = gw / 40, o = gw % 40;
  float s = 0.f;
#pragma unroll
  for (int i = 0; i < 4; ++i) {
    int j = lane + i * 64;
    s += a2[b * 256 + j] * L3W[o * 256 + j];
  }
#pragma unroll
  for (int off = 1; off < 64; off <<= 1) s += __shfl_xor(s, off, 64);
  if (lane == 0) out[b * 40 + o] = s + L3b[o];
}

// ---------------------------------------------------------------------------
extern "C" void kernel_launch(void* const* d_in, const int* in_sizes, int n_in,
                              void* d_out, int out_size, void* d_ws, size_t ws_size,
                              hipStream_t stream) {
  const float* x = (const float*)d_in[0];
  const float* W1 = (const float*)d_in[1];
  const float* W2 = (const float*)d_in[2];
  const float* W3 = (const float*)d_in[3];
  const float* W4 = (const float*)d_in[4];
  const float* W5 = (const float*)d_in[5];
  const float* g1 = (const float*)d_in[6];  const float* b1 = (const float*)d_in[7];
  const float* g2 = (const float*)d_in[8];  const float* b2 = (const float*)d_in[9];
  const float* g3 = (const float*)d_in[10]; const float* b3 = (const float*)d_in[11];
  const float* g4 = (const float*)d_in[12]; const float* b4 = (const float*)d_in[13];
  const float* g5 = (const float*)d_in[14]; const float* b5 = (const float*)d_in[15];
  const float* g6 = (const float*)d_in[16]; const float* b6 = (const float*)d_in[17];
  const float* g7 = (const float*)d_in[18]; const float* b7 = (const float*)d_in[19];
  const float* L1W = (const float*)d_in[20];
  const float* L2W = (const float*)d_in[21];
  const float* L2b = (const float*)d_in[22];
  const float* L3W = (const float*)d_in[23];
  const float* L3b = (const float*)d_in[24];

  char* w = (char*)d_ws;
  int* idxb = (int*)(w + WS_IDX);
  _Float16* y16 = (_Float16*)(w + WS_Y16);
  _Float16* y16b = (_Float16*)(w + WS_Y16B);
  _Float16* xcat16 = (_Float16*)(w + WS_XCAT16);
  _Float16* w16 = (_Float16*)(w + WS_W16);
  unsigned* fmax = (unsigned*)(w + WS_FMAX);
  float* fsum = (float*)(w + WS_FSUM);
  float* a1 = (float*)(w + WS_A1);
  float* a2 = (float*)(w + WS_A2);

  knn_prep_kernel<<<2191, 512, 0, stream>>>(x, W1, g1, b1, W2, W3, W4, W5,
                                            w16, fmax, idxb, xcat16);
  gemm1_kernel<<<256, 256, 0, stream>>>(w16, xcat16, y16);
  // fused gmax1 + gemm2 (BM=64, grid 256): y16(64ch) -> xcat[64:128] + y16b
  gemm_gather_s2<<<256, 256, 0, stream>>>(
      y16, idxb, g2, b2, w16 + 4096, xcat16, y16b);
  // fused gmax2 + gemm3 (BM=64, grid 256): y16b -> xcat[128:256] + y16(256ch)
  gemm_gather_s3<<<256, 512, 0, stream>>>(
      y16b, idxb, g3, b3, w16 + 12288, xcat16, y16);
  gmax_kernel<256, 256><<<2048, 256, 0, stream>>>(y16, idxb, g4, b4, xcat16);
  gemm5_kernel<<<dim3(64, 4), 512, 0, stream>>>(w16 + 45056, xcat16, g5, b5, fmax, fsum);
  l1_kernel<<<512, 256, 0, stream>>>(fmax, fsum, L1W, g6, b6, a1);
  l2_kernel<<<512, 256, 0, stream>>>(a1, L2W, L2b, g7, b7, a2);
  l3_kernel<<<80, 256, 0, stream>>>(a2, L3W, L3b, (float*)d_out);
}

// Round 13
// 193.783 us; speedup vs baseline: 1.1283x; 1.0430x over previous
//
#include <hip/hip_runtime.h>
#include <math.h>

// ---------------------------------------------------------------------------
// DGCNN-style network, B=8, N=2048, K=20, eval-mode BN.
// Round 24: idx-LDS staging in all three gather kernels (gmax4, gg_s2,
// gg_s3). Previously each thread loaded its point's 20 neighbor indices
// from global (8-32 threads/point redundant: ~42MB extra L2 reads in gmax4
// alone, +20 VGPRs of mm[] per thread). Now idx staged to LDS once per
// block, read in the k-loop (same-address broadcast = free). Bit-identical.
// Ledger: knn = r18 config EXACT (local optimum; r20/r22 both regressed -
// DO NOT TOUCH). gemm1 BM=64 grid 256 (r23). BM=64 fused gather-GEMMs
// (r19). Batch-aligned XCD swizzle on gather producers/consumers (r17).
// Single-gather gg3 + l1 weight-reuse (r16). gemm5 8-phase m201 (r13).
// Trick (verified r1-r10): max_k lrelu(bn(h)) == lrelu(bn(max_k h)) for bn
// scale>=0, min_k when scale<0 -> gather reduces max AND min of pre-BN y.
// ---------------------------------------------------------------------------

#define WS_IDX      0            // int[16384*20]            1,310,720 B
#define WS_Y16      1310720     // half[16384*256]          8,388,608 B  (y16a)
#define WS_XCAT16   9699328     // half[16384*512]          16,777,216 B
#define WS_W16      26476544    // half[569344]             1,138,688 B
#define WS_FMAX     27615232    // uint[8*1024]             32,768 B
#define WS_FSUM     27648000    // float[8*1024]            32,768 B
#define WS_A1       27680768    // float[8*512]             16,384 B
#define WS_A2       27697152    // float[8*256]             8,192 B
#define WS_Y16B     27705344    // half[16384*128]          4,194,304 B  (y16b)
// total ~31.9 MB

typedef _Float16 f16x8 __attribute__((ext_vector_type(8)));
typedef float f32x4 __attribute__((ext_vector_type(4)));

struct F3 { float x, y, z; };

__device__ __forceinline__ float lrelu(float v) { return (v >= 0.f) ? v : 0.2f * v; }
__device__ __forceinline__ unsigned sortable_f32(float f) {
  unsigned b = __float_as_uint(f);
  return b ^ (((unsigned)((int)b >> 31)) | 0x80000000u);
}
__device__ __forceinline__ float desort_f32(unsigned u) {
  unsigned b = (u & 0x80000000u) ? (u ^ 0x80000000u) : ~u;
  return __uint_as_float(b);
}
// batch-aligned XCD swizzle: i%8 -> XCD under round-robin dispatch; with
// per-batch chunk = nwg/8, batch(bid) = i%8. Bijective for nwg%8==0.
__device__ __forceinline__ int xcd_swz(int i, int nwg) {
  return (i & 7) * (nwg >> 3) + (i >> 3);
}

// --------------------- KNN + edge1 + prep (one dispatch) --------------------
// EXACT r18 configuration (best measured). 512 thr, 8 waves, 1 query/wave.
__global__ __launch_bounds__(512) void knn_prep_kernel(
    const float* __restrict__ x, const float* __restrict__ W1,
    const float* __restrict__ g1, const float* __restrict__ b1,
    const float* __restrict__ W2, const float* __restrict__ W3,
    const float* __restrict__ W4, const float* __restrict__ W5,
    _Float16* __restrict__ w16, unsigned* __restrict__ fzero,
    int* __restrict__ idxo, _Float16* __restrict__ xcat) {
  __shared__ F3 pts_s[2048];                    // 24576 B
  __shared__ unsigned long long cand_s[8][60];  // 3840 B
  __shared__ int sel_s[8][20];                  // 640 B
  int tid = threadIdx.x;

  if (blockIdx.x >= 2048) {  // ---- prep branch: 143 blocks x 4096 items ----
    int bid = blockIdx.x - 2048;
#pragma unroll
    for (int t = 0; t < 8; ++t) {
      int i = bid * 4096 + t * 512 + tid;
      if (i < 4096) w16[i] = (_Float16)W2[i];
      else if (i < 12288) w16[i] = (_Float16)W3[i - 4096];
      else if (i < 45056) w16[i] = (_Float16)W4[i - 12288];
      else if (i < 569344) w16[i] = (_Float16)W5[i - 45056];
      else fzero[i - 569344] = 0u;  // fmax (sortable 0 < any finite) + fsum
    }
    return;
  }

  int wv = tid >> 6, lane = tid & 63;  // wv 0..7, one query per wave
  int qbase = blockIdx.x * 8;
  int b = qbase >> 11;
  int nbase = qbase & 2047;
  const float* xb = x + b * 6144;
#pragma unroll
  for (int i = 0; i < 4; ++i) {
    int m = tid + i * 512;
    F3 p; p.x = xb[m]; p.y = xb[2048 + m]; p.z = xb[4096 + m];
    pts_s[m] = p;
  }
  __syncthreads();

  F3 q = pts_s[nbase + wv];
  float qw = q.x * q.x + q.y * q.y + q.z * q.z;
  unsigned keys[32];
  unsigned lmax = 0u;
#pragma unroll
  for (int j = 0; j < 32; ++j) {
    F3 p = pts_s[j * 64 + lane];
    float pw = p.x * p.x + p.y * p.y + p.z * p.z;
    float nd = 2.0f * (q.x * p.x + q.y * p.y + q.z * p.z) - qw - pw;
    unsigned key = sortable_f32(nd);
    keys[j] = key;
    lmax = (key > lmax) ? key : lmax;
  }
  unsigned lo = 0u, hi = 0x8001u;
  for (int it = 0; it < 16; ++it) {
    unsigned mid = (lo + hi + 1) >> 1;
    int cnt = __popcll(__ballot(lmax >= (mid << 16)));
    if (cnt >= 20) lo = mid; else hi = mid;
  }
  unsigned T = lo << 16;
  // ballot-prefix compaction (no atomics); cnt is wave-uniform
  unsigned cnt = 0u;
  unsigned long long below = (1ull << lane) - 1ull;
#pragma unroll
  for (int j = 0; j < 32; ++j) {
    int m = j * 64 + lane;
    bool pass = keys[j] >= T;
    unsigned long long mask = __ballot(pass);
    if (pass) {
      unsigned pos = cnt + (unsigned)__popcll(mask & below);
      if (pos < 60)
        cand_s[wv][pos] =
            (((unsigned long long)keys[j]) << 32) | (unsigned)(2047 - m);
    }
    cnt += (unsigned)__popcll(mask);
  }

  int row = qbase + wv;
  int outb = row * 20;
  unsigned C = cnt;  // wave-uniform
  if (C <= 60) {
    unsigned long long v = (lane < (int)C) ? ~cand_s[wv][lane] : ~0ull;
#pragma unroll
    for (int k = 2; k <= 64; k <<= 1) {
#pragma unroll
      for (int jj = k >> 1; jj > 0; jj >>= 1) {
        unsigned long long o = __shfl_xor(v, jj, 64);
        bool lower = (lane & jj) == 0;
        bool up = (lane & k) == 0;
        bool takeMin = (lower == up);
        bool sw = takeMin ? (o < v) : (o > v);
        v = sw ? o : v;
      }
    }
    if (lane < 20) {
      unsigned long long pack = ~v;
      int m = 2047 - (int)(pack & 0xFFFFFFFFu);
      idxo[outb + lane] = m;
      sel_s[wv][lane] = m;
    }
  } else {
    unsigned long long prev = ~0ull;
    for (int r = 0; r < 20; ++r) {
      unsigned long long best = 0ull;
#pragma unroll
      for (int j = 0; j < 32; ++j) {
        int m = j * 64 + lane;
        unsigned long long pk =
            (((unsigned long long)keys[j]) << 32) | (unsigned)(2047 - m);
        bool ok = (pk < prev) & (pk > best);
        best = ok ? pk : best;
      }
#pragma unroll
      for (int off = 1; off < 64; off <<= 1) {
        unsigned long long o = __shfl_xor(best, off, 64);
        best = (o > best) ? o : best;
      }
      int m = 2047 - (int)(best & 0xFFFFFFFFu);
      if (lane == 0) { idxo[outb + r] = m; sel_s[wv][r] = m; }
      prev = best;
    }
  }

  float w0 = W1[lane * 3 + 0], w1 = W1[lane * 3 + 1], w2 = W1[lane * 3 + 2];
  float inv = 1.0f / sqrtf(1.0f + 1e-5f);
  float sc = g1[lane] * inv, bi = b1[lane];
  {
    float mx = -3.4e38f, mn = 3.4e38f;
#pragma unroll
    for (int k = 0; k < 20; ++k) {
      F3 p = pts_s[sel_s[wv][k]];
      float v = w0 * p.x + w1 * p.y + w2 * p.z;
      mx = fmaxf(mx, v);
      mn = fminf(mn, v);
    }
    float v = (sc >= 0.0f) ? mx : mn;
    xcat[row * 512 + lane] = (_Float16)lrelu(sc * v + bi);
  }
}

// --------------- gather max/min + BN + lrelu -> fp16 (f16x8) ----------------
// idx staged in LDS (one load per block, broadcast reads in k-loop).
template <int C, int COFF>
__global__ __launch_bounds__(256) void gmax_kernel(const _Float16* __restrict__ y,
                                                   const int* __restrict__ idx,
                                                   const float* __restrict__ g,
                                                   const float* __restrict__ bb,
                                                   _Float16* __restrict__ xcat) {
  constexpr int TP = C / 8;        // threads per point (32 for C=256)
  constexpr int PPB = 256 / TP;    // points per block (8)
  __shared__ int idx_s[PPB][20];
  int bxs = xcd_swz(blockIdx.x, gridDim.x);
  int tid = threadIdx.x;
  int pgBase = bxs * PPB;
  if (tid < PPB * 20) idx_s[tid / 20][tid % 20] = idx[pgBase * 20 + tid];
  __syncthreads();
  int c8 = tid & (TP - 1);
  int p = tid / TP;
  int pg = pgBase + p;
  int b = pg >> 11;
  int base = b * 2048 * C + c8 * 8;
  float mx[8], mn[8];
#pragma unroll
  for (int i = 0; i < 8; ++i) { mx[i] = -3.4e38f; mn[i] = 3.4e38f; }
#pragma unroll
  for (int k = 0; k < 20; ++k) {
    f16x8 v = *(const f16x8*)&y[base + idx_s[p][k] * C];
#pragma unroll
    for (int i = 0; i < 8; ++i) {
      float f = (float)v[i];
      mx[i] = fmaxf(mx[i], f);
      mn[i] = fminf(mn[i], f);
    }
  }
  float inv = 1.0f / sqrtf(1.0f + 1e-5f);
  f16x8 outv;
#pragma unroll
  for (int i = 0; i < 8; ++i) {
    float s = g[c8 * 8 + i] * inv;
    float v = (s >= 0.0f) ? mx[i] : mn[i];
    outv[i] = (_Float16)lrelu(s * v + bb[c8 * 8 + i]);
  }
  *(f16x8*)&xcat[pg * 512 + COFF + c8 * 8] = outv;
}

// ------------- gemm1: BM=64 BN=64 K=64, grid 256, 4 waves x (16x64) --------
__global__ __launch_bounds__(256) void gemm1_kernel(
    const _Float16* __restrict__ Wh, const _Float16* __restrict__ Xc,
    _Float16* __restrict__ Y) {
  __shared__ _Float16 Xs[64 * 40];
  __shared__ _Float16 Ws[64 * 40];
  int tid = threadIdx.x;
  int lane = tid & 63, w = tid >> 6;
  int col = lane & 15, quad = lane >> 4;
  int pg0 = xcd_swz(blockIdx.x, gridDim.x) * 64;
  int r0 = tid >> 2;
  int c8 = (tid & 3) * 8;
  f32x4 acc[4] = {};
  for (int k0 = 0; k0 < 64; k0 += 32) {
    f16x8 xa = *(const f16x8*)&Xc[(pg0 + r0) * 512 + k0 + c8];
    f16x8 wa = *(const f16x8*)&Wh[r0 * 64 + k0 + c8];
    __syncthreads();
    *(f16x8*)&Xs[r0 * 40 + c8] = xa;
    *(f16x8*)&Ws[r0 * 40 + c8] = wa;
    __syncthreads();
    f16x8 af = *(const f16x8*)&Xs[(w * 16 + col) * 40 + quad * 8];
    f16x8 bf[4];
#pragma unroll
    for (int t = 0; t < 4; ++t)
      bf[t] = *(const f16x8*)&Ws[(t * 16 + col) * 40 + quad * 8];
#pragma unroll
    for (int nt = 0; nt < 4; ++nt)
      acc[nt] = __builtin_amdgcn_mfma_f32_16x16x32_f16(af, bf[nt], acc[nt], 0, 0, 0);
  }
#pragma unroll
  for (int nt = 0; nt < 4; ++nt)
#pragma unroll
    for (int r = 0; r < 4; ++r) {
      int p = pg0 + w * 16 + quad * 4 + r;
      int ch = nt * 16 + col;
      Y[p * 64 + ch] = (_Float16)acc[nt][r];
    }
}

// ----- fused gather + GEMM stage 2: BM=64, grid 256, 256 thr, 4 waves ------
__global__ __launch_bounds__(256) void gemm_gather_s2(
    const _Float16* __restrict__ y, const int* __restrict__ idx,
    const float* __restrict__ g, const float* __restrict__ bb,
    const _Float16* __restrict__ Wh, _Float16* __restrict__ xcat,
    _Float16* __restrict__ Yout) {
  constexpr int CIN = 64, COUT = 128, XOFF = 64;
  constexpr int CP = CIN + 8;  // 72
  __shared__ _Float16 As[64 * CP];
  __shared__ _Float16 Ws[COUT * 40];
  __shared__ int idx_s[64][20];
  int tid = threadIdx.x;
  int lane = tid & 63, w = tid >> 6;
  int col = lane & 15, quad = lane >> 4;
  int pg0 = xcd_swz(blockIdx.x, gridDim.x) * 64;
  const float inv = 1.0f / sqrtf(1.0f + 1e-5f);

  // ---- stage idx for the block's 64 points
  for (int t = tid; t < 64 * 20; t += 256)
    idx_s[t / 20][t % 20] = idx[pg0 * 20 + t];
  __syncthreads();

  // ---- phase A: gather + minmax + bn + lrelu -> As + xcat
  constexpr int TPR = CIN / 8;  // 8
#pragma unroll
  for (int t = 0; t < (64 * TPR) / 256; ++t) {  // 2 iters
    int task = t * 256 + tid;
    int r = task / TPR;
    int c8 = task % TPR;
    int pg = pg0 + r;
    int b = pg >> 11;
    int base = b * 2048 * CIN + c8 * 8;
    float mx[8], mn[8];
#pragma unroll
    for (int i = 0; i < 8; ++i) { mx[i] = -3.4e38f; mn[i] = 3.4e38f; }
#pragma unroll
    for (int k = 0; k < 20; ++k) {
      f16x8 v = *(const f16x8*)&y[base + idx_s[r][k] * CIN];
#pragma unroll
      for (int i = 0; i < 8; ++i) {
        float f = (float)v[i];
        mx[i] = fmaxf(mx[i], f);
        mn[i] = fminf(mn[i], f);
      }
    }
    f16x8 outv;
#pragma unroll
    for (int i = 0; i < 8; ++i) {
      float s = g[c8 * 8 + i] * inv;
      float vv = (s >= 0.0f) ? mx[i] : mn[i];
      outv[i] = (_Float16)lrelu(s * vv + bb[c8 * 8 + i]);
    }
    *(f16x8*)&As[r * CP + c8 * 8] = outv;
    *(f16x8*)&xcat[pg * 512 + XOFF + c8 * 8] = outv;
  }
  __syncthreads();

  // ---- phase B: GEMM (K=64, 2 steps). W staged: 128 rows x 32 halves.
  int r0 = tid >> 1;            // 0..127
  int c8b = (tid & 1) * 16;     // 0 or 16
  f32x4 acc[4][2] = {};
  for (int k0 = 0; k0 < CIN; k0 += 32) {
    f16x8 wa = *(const f16x8*)&Wh[r0 * CIN + k0 + c8b];
    f16x8 wb = *(const f16x8*)&Wh[r0 * CIN + k0 + c8b + 8];
    __syncthreads();
    *(f16x8*)&Ws[r0 * 40 + c8b] = wa;
    *(f16x8*)&Ws[r0 * 40 + c8b + 8] = wb;
    __syncthreads();
    f16x8 af[4], bf[2];
#pragma unroll
    for (int t = 0; t < 4; ++t)
      af[t] = *(const f16x8*)&As[(t * 16 + col) * CP + k0 + quad * 8];
#pragma unroll
    for (int t = 0; t < 2; ++t)
      bf[t] = *(const f16x8*)&Ws[(w * 32 + t * 16 + col) * 40 + quad * 8];
#pragma unroll
    for (int mt = 0; mt < 4; ++mt)
#pragma unroll
      for (int nt = 0; nt < 2; ++nt)
        acc[mt][nt] = __builtin_amdgcn_mfma_f32_16x16x32_f16(af[mt], bf[nt],
                                                             acc[mt][nt], 0, 0, 0);
  }
#pragma unroll
  for (int mt = 0; mt < 4; ++mt)
#pragma unroll
    for (int nt = 0; nt < 2; ++nt)
#pragma unroll
      for (int r = 0; r < 4; ++r) {
        int p = pg0 + mt * 16 + quad * 4 + r;
        int ch = w * 32 + nt * 16 + col;
        Yout[p * COUT + ch] = (_Float16)acc[mt][nt][r];
      }
}

// ----- fused gather + GEMM stage 3: BM=64, grid 256, 512 thr, 8 waves ------
__global__ __launch_bounds__(512) void gemm_gather_s3(
    const _Float16* __restrict__ y, const int* __restrict__ idx,
    const float* __restrict__ g, const float* __restrict__ bb,
    const _Float16* __restrict__ Wh, _Float16* __restrict__ xcat,
    _Float16* __restrict__ Yout) {
  constexpr int CIN = 128, COUT = 256, XOFF = 128;
  constexpr int CP = CIN + 8;  // 136
  __shared__ _Float16 As[64 * CP];
  __shared__ _Float16 Ws[COUT * 40];
  __shared__ int idx_s[64][20];
  int tid = threadIdx.x;
  int lane = tid & 63, w = tid >> 6;
  int col = lane & 15, quad = lane >> 4;
  int pg0 = xcd_swz(blockIdx.x, gridDim.x) * 64;
  const float inv = 1.0f / sqrtf(1.0f + 1e-5f);

  // ---- stage idx for the block's 64 points
  for (int t = tid; t < 64 * 20; t += 512)
    idx_s[t / 20][t % 20] = idx[pg0 * 20 + t];
  __syncthreads();

  // ---- phase A: gather + minmax + bn + lrelu -> As + xcat
  constexpr int TPR = CIN / 8;  // 16
#pragma unroll
  for (int t = 0; t < (64 * TPR) / 512; ++t) {  // 2 iters
    int task = t * 512 + tid;
    int r = task / TPR;
    int c8 = task % TPR;
    int pg = pg0 + r;
    int b = pg >> 11;
    int base = b * 2048 * CIN + c8 * 8;
    float mx[8], mn[8];
#pragma unroll
    for (int i = 0; i < 8; ++i) { mx[i] = -3.4e38f; mn[i] = 3.4e38f; }
#pragma unroll
    for (int k = 0; k < 20; ++k) {
      f16x8 v = *(const f16x8*)&y[base + idx_s[r][k] * CIN];
#pragma unroll
      for (int i = 0; i < 8; ++i) {
        float f = (float)v[i];
        mx[i] = fmaxf(mx[i], f);
        mn[i] = fminf(mn[i], f);
      }
    }
    f16x8 outv;
#pragma unroll
    for (int i = 0; i < 8; ++i) {
      float s = g[c8 * 8 + i] * inv;
      float vv = (s >= 0.0f) ? mx[i] : mn[i];
      outv[i] = (_Float16)lrelu(s * vv + bb[c8 * 8 + i]);
    }
    *(f16x8*)&As[r * CP + c8 * 8] = outv;
    *(f16x8*)&xcat[pg * 512 + XOFF + c8 * 8] = outv;
  }
  __syncthreads();

  // ---- phase B: GEMM (K=128, 4 steps). W staged: 256 rows x 32 halves.
  int r0 = tid >> 1;            // 0..255
  int c8b = (tid & 1) * 16;     // 0 or 16
  f32x4 acc[4][2] = {};
  for (int k0 = 0; k0 < CIN; k0 += 32) {
    f16x8 wa = *(const f16x8*)&Wh[r0 * CIN + k0 + c8b];
    f16x8 wb = *(const f16x8*)&Wh[r0 * CIN + k0 + c8b + 8];
    __syncthreads();
    *(f16x8*)&Ws[r0 * 40 + c8b] = wa;
    *(f16x8*)&Ws[r0 * 40 + c8b + 8] = wb;
    __syncthreads();
    f16x8 af[4], bf[2];
#pragma unroll
    for (int t = 0; t < 4; ++t)
      af[t] = *(const f16x8*)&As[(t * 16 + col) * CP + k0 + quad * 8];
#pragma unroll
    for (int t = 0; t < 2; ++t)
      bf[t] = *(const f16x8*)&Ws[(w * 32 + t * 16 + col) * 40 + quad * 8];
#pragma unroll
    for (int mt = 0; mt < 4; ++mt)
#pragma unroll
      for (int nt = 0; nt < 2; ++nt)
        acc[mt][nt] = __builtin_amdgcn_mfma_f32_16x16x32_f16(af[mt], bf[nt],
                                                             acc[mt][nt], 0, 0, 0);
  }
#pragma unroll
  for (int mt = 0; mt < 4; ++mt)
#pragma unroll
    for (int nt = 0; nt < 2; ++nt)
#pragma unroll
      for (int r = 0; r < 4; ++r) {
        int p = pg0 + mt * 16 + quad * 4 + r;
        int ch = w * 32 + nt * 16 + col;
        Yout[p * COUT + ch] = (_Float16)acc[mt][nt][r];
      }
}

// ------ gemm5: 8-phase 256x256 schedule, fused BN+lrelu+pool epilogue -------
typedef const __attribute__((address_space(1))) void* gas1_t;
typedef __attribute__((address_space(3))) void* las3_t;

__device__ __forceinline__ void stage16(const _Float16* g, char* l) {
  __builtin_amdgcn_global_load_lds((gas1_t)g, (las3_t)l, 16, 0, 0);
}

__global__ __launch_bounds__(512, 2) void gemm5_kernel(
    const _Float16* __restrict__ Wh, const _Float16* __restrict__ Xc,
    const float* __restrict__ g5, const float* __restrict__ b5,
    unsigned* __restrict__ fmax, float* __restrict__ fsum) {
  __shared__ __attribute__((aligned(16))) char lds[131072];
  char* ldsc = (char*)lds;
  const int tid = threadIdx.x;
  const int lane = tid & 63, w = tid >> 6;
  const int wm = w & 1, wn = w >> 1;
  const int col = lane & 15, quad = lane >> 4;
  const int pg0 = blockIdx.x * 256;
  const int o0 = blockIdx.y * 256;

  const int so = tid << 4;
  const int sl = so ^ (((so >> 9) & 3) << 5);
  const int srow0 = sl >> 7;
  const int skc0 = (sl & 127) >> 1;

#define STG(srcp, baserow, ktile, regoff, i)                                  \
  stage16((srcp) + ((baserow) + (i) * 64 + srow0) * 512 + (ktile) * 64 + skc0,\
          ldsc + (regoff) + (i) * 8192 + (w << 10))

  const int swc = ((col >> 2) & 3) << 5;
  const int labA = (col * 128 + quad * 16) ^ swc;
  const int labB = ((wn & 1) * 8192 + col * 128 + quad * 16) ^ swc;

#define RDA(m, kk) (*(const f16x8*)(rA + ((labA ^ ((kk) << 6)) + (m) * 2048)))
#define RDB(n, kk) (*(const f16x8*)(rB + ((labB ^ ((kk) << 6)) + (n) * 2048)))

  f32x4 acc[8][4] = {};

  STG(Wh, o0, 0, 32768, 0);       STG(Wh, o0, 0, 32768, 1);        // B0
  STG(Wh, o0 + 128, 0, 49152, 0); STG(Wh, o0 + 128, 0, 49152, 1);  // B1
  STG(Xc, pg0, 0, 0, 0);          STG(Xc, pg0 + 128, 0, 16384, 0); // A i0
  STG(Xc, pg0, 0, 0, 1);          STG(Xc, pg0 + 128, 0, 16384, 1); // A i1
  asm volatile("s_waitcnt vmcnt(0)" ::: "memory");
  __builtin_amdgcn_s_barrier();

  for (int t = 0; t < 8; ++t) {
    const int nt = t + 1;
    const char* rA = ldsc + (t & 1) * 65536 + wm * 16384;
    const char* rB = ldsc + (t & 1) * 65536 + 32768 + (wn >> 1) * 16384;
    const int nreg = (nt & 1) * 65536;
    f16x8 bf[4][2];
#pragma unroll
    for (int p = 0; p < 4; ++p) {
      f16x8 a[2][2];
#pragma unroll
      for (int mm = 0; mm < 2; ++mm)
#pragma unroll
        for (int kk = 0; kk < 2; ++kk)
          a[mm][kk] = RDA(2 * p + mm, kk);
      if (p == 0) {
#pragma unroll
        for (int n = 0; n < 4; ++n)
#pragma unroll
          for (int kk = 0; kk < 2; ++kk)
            bf[n][kk] = RDB(n, kk);
      }
      if (t < 7) {
        if (p == 0) { STG(Wh, o0, nt, nreg + 32768, 0);
                      STG(Wh, o0, nt, nreg + 32768, 1); }
        if (p == 1) { STG(Wh, o0 + 128, nt, nreg + 49152, 0);
                      STG(Wh, o0 + 128, nt, nreg + 49152, 1); }
        if (p == 2) { STG(Xc, pg0, nt, nreg + 0, 0);
                      STG(Xc, pg0 + 128, nt, nreg + 16384, 0); }
        if (p == 3) { STG(Xc, pg0, nt, nreg + 0, 1);
                      STG(Xc, pg0 + 128, nt, nreg + 16384, 1); }
      }
      if (p == 1) {
        if (t < 7) { asm volatile("s_waitcnt vmcnt(4)" ::: "memory"); }
        else       { asm volatile("s_waitcnt vmcnt(0)" ::: "memory"); }
      }
      if (p == 3 && t < 7) {
        asm volatile("s_waitcnt vmcnt(2)" ::: "memory");
      }
      __builtin_amdgcn_s_barrier();
      asm volatile("s_waitcnt lgkmcnt(0)" ::: "memory");
      __builtin_amdgcn_sched_barrier(0);
      __builtin_amdgcn_s_setprio(1);
#pragma unroll
      for (int mm = 0; mm < 2; ++mm)
#pragma unroll
        for (int n = 0; n < 4; ++n)
#pragma unroll
          for (int kk = 0; kk < 2; ++kk)
            acc[2 * p + mm][n] = __builtin_amdgcn_mfma_f32_16x16x32_f16(
                a[mm][kk], bf[n][kk], acc[2 * p + mm][n], 0, 0, 0);
      __builtin_amdgcn_s_setprio(0);
      __builtin_amdgcn_s_barrier();
    }
  }
#undef STG
#undef RDA
#undef RDB

  const float inv = 1.0f / sqrtf(1.0f + 1e-5f);
  const int b = pg0 >> 11;
#pragma unroll
  for (int n = 0; n < 4; ++n) {
    int ch = o0 + wn * 64 + n * 16 + col;
    float sc = g5[ch] * inv, bi = b5[ch];
    float mx = -3.4e38f, sm = 0.f;
#pragma unroll
    for (int m = 0; m < 8; ++m)
#pragma unroll
      for (int r = 0; r < 4; ++r) {
        float v = lrelu(acc[m][n][r] * sc + bi);
        mx = fmaxf(mx, v);
        sm += v;
      }
    mx = fmaxf(mx, __shfl_xor(mx, 16, 64));
    sm += __shfl_xor(sm, 16, 64);
    mx = fmaxf(mx, __shfl_xor(mx, 32, 64));
    sm += __shfl_xor(sm, 32, 64);
    if (quad == 0) {
      atomicMax(&fmax[b * 1024 + ch], sortable_f32(mx));
      atomicAdd(&fsum[b * 1024 + ch], sm);
    }
  }
}

// ------------------------------ MLP head ------------------------------------
// l1: one block per output o; L1W row in registers, reused for all 8 batches.
__global__ __launch_bounds__(256) void l1_kernel(const unsigned* __restrict__ fmax,
                                                 const float* __restrict__ fsum,
                                                 const float* __restrict__ L1W,
                                                 const float* __restrict__ g6,
                                                 const float* __restrict__ b6,
                                                 float* __restrict__ a1) {
  __shared__ float red[4][8];
  int o = blockIdx.x;
  int tid = threadIdx.x, wv = tid >> 6;
  float4 w0 = *(const float4*)&L1W[o * 2048 + tid * 8];
  float4 w1 = *(const float4*)&L1W[o * 2048 + tid * 8 + 4];
  bool isMax = (tid < 128);
  float sb[8];
#pragma unroll
  for (int b = 0; b < 8; ++b) {
    float s;
    if (isMax) {
      uint4 a0 = *(const uint4*)&fmax[b * 1024 + tid * 8];
      uint4 a1v = *(const uint4*)&fmax[b * 1024 + tid * 8 + 4];
      s = desort_f32(a0.x) * w0.x + desort_f32(a0.y) * w0.y +
          desort_f32(a0.z) * w0.z + desort_f32(a0.w) * w0.w +
          desort_f32(a1v.x) * w1.x + desort_f32(a1v.y) * w1.y +
          desort_f32(a1v.z) * w1.z + desort_f32(a1v.w) * w1.w;
    } else {
      float4 f0 = *(const float4*)&fsum[b * 1024 + tid * 8 - 1024];
      float4 f1 = *(const float4*)&fsum[b * 1024 + tid * 8 - 1020];
      s = (f0.x * w0.x + f0.y * w0.y + f0.z * w0.z + f0.w * w0.w +
           f1.x * w1.x + f1.y * w1.y + f1.z * w1.z + f1.w * w1.w) *
          (1.0f / 2048.0f);
    }
    sb[b] = s;
  }
#pragma unroll
  for (int b = 0; b < 8; ++b)
#pragma unroll
    for (int off = 1; off < 64; off <<= 1) sb[b] += __shfl_xor(sb[b], off, 64);
  if ((tid & 63) == 0) {
#pragma unroll
    for (int b = 0; b < 8; ++b) red[wv][b] = sb[b];
  }
  __syncthreads();
  if (tid < 8) {
    float s = red[0][tid] + red[1][tid] + red[2][tid] + red[3][tid];
    float scv = g6[o] / sqrtf(1.0f + 1e-5f);
    a1[tid * 512 + o] = lrelu(s * scv + b6[o]);
  }
}

__global__ __launch_bounds__(256) void l2_kernel(const float* __restrict__ a1,
                                                 const float* __restrict__ L2W,
                                                 const float* __restrict__ L2b,
                                                 const float* __restrict__ g7,
                                                 const float* __restrict__ b7,
                                                 float* __restrict__ a2) {
  int gw = (blockIdx.x * 256 + threadIdx.x) >> 6;  // 2048 waves
  int lane = threadIdx.x & 63;
  int b = gw >> 8, o = gw & 255;
  float s = 0.f;
#pragma unroll
  for (int i = 0; i < 8; ++i) {
    int j = lane + i * 64;
    s += a1[b * 512 + j] * L2W[o * 512 + j];
  }
#pragma unroll
  for (int off = 1; off < 64; off <<= 1) s += __shfl_xor(s, off, 64);
  if (lane == 0) {
    float v = s + L2b[o];
    float scv = g7[o] / sqrtf(1.0f + 1e-5f);
    a2[b * 256 + o] = lrelu(v * scv + b7[o]);
  }
}

__global__ __launch_bounds__(256) void l3_kernel(const float* __restrict__ a2,
                                                 const float* __restrict__ L3W,
                                                 const float* __restrict__ L3b,
                                                 float* __restrict__ out) {
  int gw = (blockIdx.x * 256 + threadIdx.x) >> 6;  // 320 waves
  int lane = threadIdx.x & 63;
  int b = gw / 40, o = gw % 40;
  float s = 0.f;
#pragma unroll
  for (int i = 0; i < 4; ++i) {
    int j = lane + i * 64;
    s += a2[b * 256 + j] * L3W[o * 256 + j];
  }
#pragma unroll
  for (int off = 1; off < 64; off <<= 1) s += __shfl_xor(s, off, 64);
  if (lane == 0) out[b * 40 + o] = s + L3b[o];
}

// ---------------------------------------------------------------------------
extern "C" void kernel_launch(void* const* d_in, const int* in_sizes, int n_in,
                              void* d_out, int out_size, void* d_ws, size_t ws_size,
                              hipStream_t stream) {
  const float* x = (const float*)d_in[0];
  const float* W1 = (const float*)d_in[1];
  const float* W2 = (const float*)d_in[2];
  const float* W3 = (const float*)d_in[3];
  const float* W4 = (const float*)d_in[4];
  const float* W5 = (const float*)d_in[5];
  const float* g1 = (const float*)d_in[6];  const float* b1 = (const float*)d_in[7];
  const float* g2 = (const float*)d_in[8];  const float* b2 = (const float*)d_in[9];
  const float* g3 = (const float*)d_in[10]; const float* b3 = (const float*)d_in[11];
  const float* g4 = (const float*)d_in[12]; const float* b4 = (const float*)d_in[13];
  const float* g5 = (const float*)d_in[14]; const float* b5 = (const float*)d_in[15];
  const float* g6 = (const float*)d_in[16]; const float* b6 = (const float*)d_in[17];
  const float* g7 = (const float*)d_in[18]; const float* b7 = (const float*)d_in[19];
  const float* L1W = (const float*)d_in[20];
  const float* L2W = (const float*)d_in[21];
  const float* L2b = (const float*)d_in[22];
  const float* L3W = (const float*)d_in[23];
  const float* L3b = (const float*)d_in[24];

  char* w = (char*)d_ws;
  int* idxb = (int*)(w + WS_IDX);
  _Float16* y16 = (_Float16*)(w + WS_Y16);
  _Float16* y16b = (_Float16*)(w + WS_Y16B);
  _Float16* xcat16 = (_Float16*)(w + WS_XCAT16);
  _Float16* w16 = (_Float16*)(w + WS_W16);
  unsigned* fmax = (unsigned*)(w + WS_FMAX);
  float* fsum = (float*)(w + WS_FSUM);
  float* a1 = (float*)(w + WS_A1);
  float* a2 = (float*)(w + WS_A2);

  knn_prep_kernel<<<2191, 512, 0, stream>>>(x, W1, g1, b1, W2, W3, W4, W5,
                                            w16, fmax, idxb, xcat16);
  gemm1_kernel<<<256, 256, 0, stream>>>(w16, xcat16, y16);
  // fused gmax1 + gemm2 (BM=64, grid 256): y16(64ch) -> xcat[64:128] + y16b
  gemm_gather_s2<<<256, 256, 0, stream>>>(
      y16, idxb, g2, b2, w16 + 4096, xcat16, y16b);
  // fused gmax2 + gemm3 (BM=64, grid 256): y16b -> xcat[128:256] + y16(256ch)
  gemm_gather_s3<<<256, 512, 0, stream>>>(
      y16b, idxb, g3, b3, w16 + 12288, xcat16, y16);
  gmax_kernel<256, 256><<<2048, 256, 0, stream>>>(y16, idxb, g4, b4, xcat16);
  gemm5_kernel<<<dim3(64, 4), 512, 0, stream>>>(w16 + 45056, xcat16, g5, b5, fmax, fsum);
  l1_kernel<<<512, 256, 0, stream>>>(fmax, fsum, L1W, g6, b6, a1);
  l2_kernel<<<512, 256, 0, stream>>>(a1, L2W, L2b, g7, b7, a2);
  l3_kernel<<<80, 256, 0, stream>>>(a2, L3W, L3b, (float*)d_out);
}